// Round 7
// baseline (348.346 us; speedup 1.0000x reference)
//
#include <hip/hip_runtime.h>

// Problem constants (match reference)
#define NN 20000
#define MM 2000
#define EE 320000
#define NSLICE 8
#define NBC 1250  // EE/256 exactly
static constexpr float SLOPE = 0.2f;
static constexpr float EPSBN = 1e-5f;

__device__ inline float4 f4add(float4 a, float4 b) {
  return make_float4(a.x + b.x, a.y + b.y, a.z + b.z, a.w + b.w);
}
__device__ inline float4 f4fma(float a, float4 v, float4 c) {
  return make_float4(c.x + a * v.x, c.y + a * v.y, c.z + a * v.z, c.w + a * v.w);
}
__device__ inline float leaky(float v) { return (v > 0.f) ? v : SLOPE * v; }

// per-thread BN scale/shift for 4 channels (f4 index c4)
__device__ inline void bn_sc4(const float* __restrict__ st, const float* __restrict__ g,
                              const float* __restrict__ be, float ninv, int c4,
                              float4& sc, float4& sh) {
  float* scp = &sc.x;
  float* shp = &sh.x;
#pragma unroll
  for (int j = 0; j < 4; j++) {
    int c = c4 * 4 + j;
    float mu = st[c] * ninv;
    float var = st[128 + c] * ninv - mu * mu;
    float s = g[c] * rsqrtf(var + EPSBN);
    scp[j] = s;
    shp[j] = be[c] - mu * s;
  }
}

// ---------------------------------------------------------------------------
// CSR count (XCD-sliced counters) + both layers' UVT folded into tail blocks.
// ---------------------------------------------------------------------------
__global__ void k_count_uv(const int* __restrict__ ni, const int* __restrict__ ei,
                           int* cntN, int* cntE, int* __restrict__ rank_n,
                           int* __restrict__ rank_e, const float* __restrict__ linw1,
                           const float* __restrict__ att1, float* __restrict__ UVT1,
                           const float* __restrict__ linw2,
                           const float* __restrict__ att2, float* __restrict__ UVT2) {
  int b = blockIdx.x;
  if (b < NBC) {
    int e = b * 256 + threadIdx.x;
    int s = b & (NSLICE - 1);
    rank_n[e] = atomicAdd(&cntN[s * NN + ni[e]], 1);
    rank_e[e] = atomicAdd(&cntE[s * MM + ei[e]], 1);
  } else if (b < NBC + 2) {
    constexpr int H = 4;
    int idx = (b - NBC) * 256 + threadIdx.x;
    int h = idx >> 7, k = idx & 127;
    float u = 0.f, v = 0.f;
    for (int c = 0; c < 128; c++) {
      float w = linw1[(size_t)k * (128 * H) + h * 128 + c];
      u += w * att1[h * 256 + c];
      v += w * att1[h * 256 + 128 + c];
    }
    UVT1[h * 128 + k] = u;
    UVT1[(H + h) * 128 + k] = v;
  } else {
    if (threadIdx.x >= 128) return;
    int k = threadIdx.x;
    float u = 0.f, v = 0.f;
    for (int c = 0; c < 128; c++) {
      float w = linw2[(size_t)k * 128 + c];
      u += w * att2[c];
      v += w * att2[128 + c];
    }
    UVT2[k] = u;
    UVT2[128 + k] = v;
  }
}

// ---------------------------------------------------------------------------
// Dual single-block scan with the per-key slice-scan folded in.
// block 0: nodes, block 1: edges. cnt[s][key] becomes within-key slice base.
// ---------------------------------------------------------------------------
__global__ __launch_bounds__(1024) void k_scan2(int* __restrict__ cntN,
                                                int* __restrict__ noff,
                                                int* __restrict__ cntE,
                                                int* __restrict__ eoff) {
  int* cnt = blockIdx.x ? cntE : cntN;
  int* off = blockIdx.x ? eoff : noff;
  int n = blockIdx.x ? MM : NN;
  __shared__ int swav[16];
  __shared__ int sCarry;
  int t = threadIdx.x;
  int lane = t & 63, wid = t >> 6;
  if (t == 0) sCarry = 0;
  __syncthreads();
  for (int base = 0; base < n; base += 1024) {
    int i = base + t;
    int v = 0;
    if (i < n) {
      int run = 0;
#pragma unroll
      for (int s = 0; s < NSLICE; s++) {
        int c = cnt[s * n + i];
        cnt[s * n + i] = run;
        run += c;
      }
      v = run;
    }
    int x = v;
#pragma unroll
    for (int o = 1; o < 64; o <<= 1) {
      int y = __shfl_up(x, o);
      if (lane >= o) x += y;
    }
    if (lane == 63) swav[wid] = x;
    __syncthreads();
    if (wid == 0) {
      int s = (lane < 16) ? swav[lane] : 0;
#pragma unroll
      for (int o = 1; o < 16; o <<= 1) {
        int y = __shfl_up(s, o);
        if (lane >= o) s += y;
      }
      if (lane < 16) swav[lane] = s;
    }
    __syncthreads();
    int wpre = wid ? swav[wid - 1] : 0;
    int total = swav[15];
    if (i < n) off[i] = sCarry + wpre + x - v;
    __syncthreads();
    if (t == 0) sCarry += total;
    __syncthreads();
  }
  if (t == 0) off[n] = sCarry;
}

// ---------------------------------------------------------------------------
// Atomic-free fill, XCD-partitioned WRITES: 8 blocks visit each chunk; block
// with slice s writes only destinations in [s*EE/8, (s+1)*EE/8) so every
// 64B line of em_n / npos_e is written from a single XCD's L2.
// ---------------------------------------------------------------------------
__global__ void k_fill(const int* __restrict__ ni, const int* __restrict__ ei,
                       const int* __restrict__ noff, const int* __restrict__ eoff,
                       const int* __restrict__ cntN, const int* __restrict__ cntE,
                       const int* __restrict__ rank_n, const int* __restrict__ rank_e,
                       int* __restrict__ em_n, int2* __restrict__ npos_e) {
  int chunk = blockIdx.x >> 3;
  int s = blockIdx.x & (NSLICE - 1);
  int e = chunk * 256 + threadIdx.x;
  int so = chunk & (NSLICE - 1);  // slice used by k_count for this chunk
  int n = ni[e];
  int m = ei[e];
  int pn = noff[n] + cntN[so * NN + n] + rank_n[e];
  int pe = eoff[m] + cntE[so * MM + m] + rank_e[e];
  const int SH = EE / NSLICE;  // 40000
  if (pn / SH == s) em_n[pn] = m;
  if (pe / SH == s) npos_e[pe] = make_int2(n, pn);
}

// ---------------------------------------------------------------------------
// Tiled GEMM: out = maybe_resid + leaky(BNopt(A)[rows,128] @ W[128,128] + b)
// Fused column stats (sum,sumsq) of the OUTPUT -> atomicAdd into stout.
// ---------------------------------------------------------------------------
__global__ __launch_bounds__(256) void k_gemm128(
    const float* __restrict__ A, const float* __restrict__ W,
    const float* __restrict__ bias, const float* __restrict__ resid,
    const float* __restrict__ st, const float* __restrict__ g,
    const float* __restrict__ be, float ninv, float* __restrict__ out,
    float* __restrict__ stout, int rows) {
  __shared__ float As[32][68];
  __shared__ float Ws[32][132];
  __shared__ float scs[128], shs[128];
  if (st && threadIdx.x < 128) {
    int c = threadIdx.x;
    float mu = st[c] * ninv;
    float var = st[128 + c] * ninv - mu * mu;
    float s = g[c] * rsqrtf(var + EPSBN);
    scs[c] = s;
    shs[c] = be[c] - mu * s;
  }
  if (st) __syncthreads();
  int tx = threadIdx.x & 15, ty = threadIdx.x >> 4;
  int r0 = blockIdx.x * 64;
  float4 acc[4][2];
#pragma unroll
  for (int j = 0; j < 4; j++) acc[j][0] = acc[j][1] = make_float4(0.f, 0.f, 0.f, 0.f);

  for (int k0 = 0; k0 < 128; k0 += 32) {
    __syncthreads();
    {
      int row = threadIdx.x >> 2, kq = threadIdx.x & 3;
      int rr = r0 + row;
      float4 a0 = make_float4(0.f, 0.f, 0.f, 0.f), a1 = a0;
      if (rr < rows) {
        const float* ap = A + (size_t)rr * 128 + k0 + kq * 8;
        a0 = ((const float4*)ap)[0];
        a1 = ((const float4*)ap)[1];
      }
      int kb = k0 + kq * 8;
      if (st) {
        a0.x = a0.x * scs[kb + 0] + shs[kb + 0];
        a0.y = a0.y * scs[kb + 1] + shs[kb + 1];
        a0.z = a0.z * scs[kb + 2] + shs[kb + 2];
        a0.w = a0.w * scs[kb + 3] + shs[kb + 3];
        a1.x = a1.x * scs[kb + 4] + shs[kb + 4];
        a1.y = a1.y * scs[kb + 5] + shs[kb + 5];
        a1.z = a1.z * scs[kb + 6] + shs[kb + 6];
        a1.w = a1.w * scs[kb + 7] + shs[kb + 7];
      }
      int kl = kq * 8;
      As[kl + 0][row] = a0.x;
      As[kl + 1][row] = a0.y;
      As[kl + 2][row] = a0.z;
      As[kl + 3][row] = a0.w;
      As[kl + 4][row] = a1.x;
      As[kl + 5][row] = a1.y;
      As[kl + 6][row] = a1.z;
      As[kl + 7][row] = a1.w;
    }
    {
      int kk = threadIdx.x >> 3, cq = threadIdx.x & 7;
      const float* wp = W + (size_t)(k0 + kk) * 128 + cq * 16;
#pragma unroll
      for (int f = 0; f < 4; f++)
        *(float4*)&Ws[kk][cq * 16 + f * 4] = ((const float4*)wp)[f];
    }
    __syncthreads();
#pragma unroll
    for (int kk = 0; kk < 32; kk++) {
      float4 a = *(const float4*)&As[kk][ty * 4];
      float4 w0 = *(const float4*)&Ws[kk][tx * 8];
      float4 w1 = *(const float4*)&Ws[kk][tx * 8 + 4];
      acc[0][0] = f4fma(a.x, w0, acc[0][0]);
      acc[0][1] = f4fma(a.x, w1, acc[0][1]);
      acc[1][0] = f4fma(a.y, w0, acc[1][0]);
      acc[1][1] = f4fma(a.y, w1, acc[1][1]);
      acc[2][0] = f4fma(a.z, w0, acc[2][0]);
      acc[2][1] = f4fma(a.z, w1, acc[2][1]);
      acc[3][0] = f4fma(a.w, w0, acc[3][0]);
      acc[3][1] = f4fma(a.w, w1, acc[3][1]);
    }
  }
  float4 b0 = ((const float4*)bias)[tx * 2];
  float4 b1 = ((const float4*)bias)[tx * 2 + 1];
  float4 cs0 = make_float4(0.f, 0.f, 0.f, 0.f), cs1 = cs0, cq0 = cs0, cq1 = cs0;
#pragma unroll
  for (int j = 0; j < 4; j++) {
    int r = r0 + ty * 4 + j;
    if (r < rows) {
      float4 o0 = acc[j][0], o1 = acc[j][1];
      o0 = make_float4(leaky(o0.x + b0.x), leaky(o0.y + b0.y), leaky(o0.z + b0.z),
                       leaky(o0.w + b0.w));
      o1 = make_float4(leaky(o1.x + b1.x), leaky(o1.y + b1.y), leaky(o1.z + b1.z),
                       leaky(o1.w + b1.w));
      if (resid) {
        float4 r0v = ((const float4*)resid)[(size_t)r * 32 + tx * 2];
        float4 r1v = ((const float4*)resid)[(size_t)r * 32 + tx * 2 + 1];
        o0 = f4add(o0, r0v);
        o1 = f4add(o1, r1v);
      }
      ((float4*)out)[(size_t)r * 32 + tx * 2] = o0;
      ((float4*)out)[(size_t)r * 32 + tx * 2 + 1] = o1;
      cs0 = f4add(cs0, o0);
      cs1 = f4add(cs1, o1);
      cq0 = make_float4(cq0.x + o0.x * o0.x, cq0.y + o0.y * o0.y, cq0.z + o0.z * o0.z,
                        cq0.w + o0.w * o0.w);
      cq1 = make_float4(cq1.x + o1.x * o1.x, cq1.y + o1.y * o1.y, cq1.z + o1.z * o1.z,
                        cq1.w + o1.w * o1.w);
    }
  }
  // fused column stats: reuse As (sum) / Ws (sumsq) LDS as [16][128]
  __syncthreads();
  float* sumb = &As[0][0];
  float* sqb = &Ws[0][0];
  *(float4*)&sumb[ty * 128 + tx * 8] = cs0;
  *(float4*)&sumb[ty * 128 + tx * 8 + 4] = cs1;
  *(float4*)&sqb[ty * 128 + tx * 8] = cq0;
  *(float4*)&sqb[ty * 128 + tx * 8 + 4] = cq1;
  __syncthreads();
  if (threadIdx.x < 128) {
    float S = 0.f, Q = 0.f;
#pragma unroll
    for (int w = 0; w < 16; w++) {
      S += sumb[w * 128 + threadIdx.x];
      Q += sqb[w * 128 + threadIdx.x];
    }
    atomicAdd(&stout[threadIdx.x], S);
    atomicAdd(&stout[128 + threadIdx.x], Q);
  }
}

// ---------------------------------------------------------------------------
// out_e[m][h][c] = (wedge[m]/deg) * (T[h][m][:] @ lin_w[:, h*128 + c])
// 32-row tiles for occupancy (grid (63,H)).
// ---------------------------------------------------------------------------
template <int H>
__global__ __launch_bounds__(256) void k_oute32(const float* __restrict__ T,
                                                const float* __restrict__ linw,
                                                const int* __restrict__ eoff,
                                                const float* __restrict__ wedge,
                                                float* __restrict__ oute) {
  int h = blockIdx.y;
  __shared__ float As[32][36];   // [k][row], 32 rows
  __shared__ float Ws[32][132];  // [k][col]
  int tx = threadIdx.x & 15, ty = threadIdx.x >> 4;
  int r0 = blockIdx.x * 32;
  const float* A = T + (size_t)h * MM * 128;
  float4 acc[2][2];
#pragma unroll
  for (int j = 0; j < 2; j++) acc[j][0] = acc[j][1] = make_float4(0.f, 0.f, 0.f, 0.f);

  for (int k0 = 0; k0 < 128; k0 += 32) {
    __syncthreads();
    {
      int row = threadIdx.x >> 3, kq = threadIdx.x & 7;
      int rr = r0 + row;
      float4 a0 = make_float4(0.f, 0.f, 0.f, 0.f);
      if (rr < MM) a0 = *(const float4*)(A + (size_t)rr * 128 + k0 + kq * 4);
      int kb = kq * 4;
      As[kb + 0][row] = a0.x;
      As[kb + 1][row] = a0.y;
      As[kb + 2][row] = a0.z;
      As[kb + 3][row] = a0.w;
    }
    {
      int kk = threadIdx.x >> 3, cq = threadIdx.x & 7;
      const float* wp = linw + (size_t)(k0 + kk) * (128 * H) + h * 128 + cq * 16;
#pragma unroll
      for (int f = 0; f < 4; f++)
        *(float4*)&Ws[kk][cq * 16 + f * 4] = ((const float4*)wp)[f];
    }
    __syncthreads();
#pragma unroll
    for (int kk = 0; kk < 32; kk++) {
      float a0 = As[kk][ty * 2], a1 = As[kk][ty * 2 + 1];
      float4 w0 = *(const float4*)&Ws[kk][tx * 8];
      float4 w1 = *(const float4*)&Ws[kk][tx * 8 + 4];
      acc[0][0] = f4fma(a0, w0, acc[0][0]);
      acc[0][1] = f4fma(a0, w1, acc[0][1]);
      acc[1][0] = f4fma(a1, w0, acc[1][0]);
      acc[1][1] = f4fma(a1, w1, acc[1][1]);
    }
  }
#pragma unroll
  for (int j = 0; j < 2; j++) {
    int m = r0 + ty * 2 + j;
    if (m >= MM) break;
    int d = eoff[m + 1] - eoff[m];
    float bv = (d > 0) ? wedge[m] / (float)d : 0.f;
    float4 o0 = acc[j][0], o1 = acc[j][1];
    o0 = make_float4(bv * o0.x, bv * o0.y, bv * o0.z, bv * o0.w);
    o1 = make_float4(bv * o1.x, bv * o1.y, bv * o1.z, bv * o1.w);
    ((float4*)oute)[((size_t)m * H + h) * 32 + tx * 2] = o0;
    ((float4*)oute)[((size_t)m * H + h) * 32 + tx * 2 + 1] = o1;
  }
}

// ---------------------------------------------------------------------------
// BatchNorm column stats (sum, sumsq) -- standalone (for phase9 outputs)
// ---------------------------------------------------------------------------
__global__ __launch_bounds__(256) void k_colstats(const float4* __restrict__ X4,
                                                  int rows, float* __restrict__ st) {
  int c4 = threadIdx.x & 31, rs = threadIdx.x >> 5, wid = threadIdx.x >> 6;
  int r0 = blockIdx.x * 256;
  int rend = min(r0 + 256, rows);
  float4 s = make_float4(0.f, 0.f, 0.f, 0.f), q = s;
  for (int r = r0 + rs; r < rend; r += 8) {
    float4 v = X4[(size_t)r * 32 + c4];
    s = f4add(s, v);
    q = make_float4(q.x + v.x * v.x, q.y + v.y * v.y, q.z + v.z * v.z, q.w + v.w * v.w);
  }
  s.x += __shfl_xor(s.x, 32); s.y += __shfl_xor(s.y, 32);
  s.z += __shfl_xor(s.z, 32); s.w += __shfl_xor(s.w, 32);
  q.x += __shfl_xor(q.x, 32); q.y += __shfl_xor(q.y, 32);
  q.z += __shfl_xor(q.z, 32); q.w += __shfl_xor(q.w, 32);
  __shared__ float4 red[4][32][2];
  if ((threadIdx.x & 63) < 32) {
    red[wid][c4][0] = s;
    red[wid][c4][1] = q;
  }
  __syncthreads();
  if (threadIdx.x < 32) {
    float4 S = f4add(f4add(red[0][threadIdx.x][0], red[1][threadIdx.x][0]),
                     f4add(red[2][threadIdx.x][0], red[3][threadIdx.x][0]));
    float4 Q = f4add(f4add(red[0][threadIdx.x][1], red[1][threadIdx.x][1]),
                     f4add(red[2][threadIdx.x][1], red[3][threadIdx.x][1]));
    int c = threadIdx.x * 4;
    atomicAdd(&st[c + 0], S.x);
    atomicAdd(&st[c + 1], S.y);
    atomicAdd(&st[c + 2], S.z);
    atomicAdd(&st[c + 3], S.w);
    atomicAdd(&st[128 + c + 0], Q.x);
    atomicAdd(&st[128 + c + 1], Q.y);
    atomicAdd(&st[128 + c + 2], Q.z);
    atomicAdd(&st[128 + c + 3], Q.w);
  }
}

// final: out = BN(X) computed from raw stats
__global__ void k_bnapply_final(const float4* __restrict__ X4,
                                const float* __restrict__ st,
                                const float* __restrict__ g,
                                const float* __restrict__ be, float ninv,
                                float4* __restrict__ Y4, int total4) {
  int i = blockIdx.x * 256 + threadIdx.x;
  if (i >= total4) return;
  int c4 = i & 31;
  float4 sc, sh;
  bn_sc4(st, g, be, ninv, c4, sc, sh);
  float4 v = X4[i];
  Y4[i] = make_float4(v.x * sc.x + sh.x, v.y * sc.y + sh.y, v.z * sc.z + sh.z,
                      v.w * sc.w + sh.w);
}

// dotx[n,h] = BN(X)[n,:] . U[:,h] ; hv[n,h] = BN(X)[n,:] . V[:,h]
template <int H>
__global__ void k_dots(const float4* __restrict__ X4, int rows,
                       const float* __restrict__ UVT, const float* __restrict__ st,
                       const float* __restrict__ g, const float* __restrict__ be,
                       float ninv, float* __restrict__ dotx, float* __restrict__ hv) {
  __shared__ float4 Ut[2 * H * 32];
  __shared__ float4 scl[32], shl[32];
  if (threadIdx.x < 32) {
    float4 sc, sh;
    bn_sc4(st, g, be, ninv, threadIdx.x, sc, sh);
    scl[threadIdx.x] = sc;
    shl[threadIdx.x] = sh;
  }
  for (int i = threadIdx.x; i < 2 * H * 32; i += 256) Ut[i] = ((const float4*)UVT)[i];
  __syncthreads();
  int idx = blockIdx.x * 256 + threadIdx.x;
  if (idx >= rows * 2 * H) return;
  int n = idx / (2 * H), h2 = idx - n * (2 * H);
  const float4* xr = X4 + (size_t)n * 32;
  const float4* ur = Ut + h2 * 32;
  float s = 0.f;
#pragma unroll 8
  for (int q = 0; q < 32; q++) {
    float4 a = xr[q], b = ur[q], c = scl[q], d = shl[q];
    float ax = a.x * c.x + d.x, ay = a.y * c.y + d.y;
    float az = a.z * c.z + d.z, aw = a.w * c.w + d.w;
    s += ax * b.x + ay * b.y + az * b.z + aw * b.w;
  }
  if (h2 < H)
    dotx[n * H + h2] = s;
  else
    hv[n * H + (h2 - H)] = s;
}

// dota[m,h] = sum over incidences of edge m of hv[node, h]
template <int H>
__global__ void k_dota(const float* __restrict__ hv, const int* __restrict__ eoff,
                       const int2* __restrict__ npos_e, float* __restrict__ dota) {
  int lane = threadIdx.x & 63;
  int m = blockIdx.x * 4 + (threadIdx.x >> 6);
  int s = eoff[m], t = eoff[m + 1];
  if (H == 4) {
    float4 acc = make_float4(0.f, 0.f, 0.f, 0.f);
    const float4* hv4 = (const float4*)hv;
    for (int j = s + lane; j < t; j += 64) acc = f4add(acc, hv4[npos_e[j].x]);
#pragma unroll
    for (int o = 32; o >= 1; o >>= 1) {
      acc.x += __shfl_xor(acc.x, o);
      acc.y += __shfl_xor(acc.y, o);
      acc.z += __shfl_xor(acc.z, o);
      acc.w += __shfl_xor(acc.w, o);
    }
    if (lane == 0) ((float4*)dota)[m] = acc;
  } else {
    float acc = 0.f;
    for (int j = s + lane; j < t; j += 64) acc += hv[npos_e[j].x];
#pragma unroll
    for (int o = 32; o >= 1; o >>= 1) acc += __shfl_xor(acc, o);
    if (lane == 0) dota[m] = acc;
  }
}

// ---------------------------------------------------------------------------
// Per-node segment softmax; alpha stored in node-CSR order.
// ---------------------------------------------------------------------------
template <int H>
__global__ void k_softmax(const int* __restrict__ noff, const int* __restrict__ em_n,
                          const float* __restrict__ dotx, const float* __restrict__ dota,
                          const float* __restrict__ wedge, float* __restrict__ alpha,
                          float* __restrict__ Dinv) {
  int lane = threadIdx.x & 63;
  int n = blockIdx.x * 4 + (threadIdx.x >> 6);
  int s = noff[n], t = noff[n + 1];
  int deg = t - s;
  int h = lane & (H - 1);
  float dx = dotx[n * H + h];
  if (deg <= 64) {
    int em0 = 0;
    float dd = 0.f;
    if (lane < deg) {
      em0 = em_n[s + lane];
      dd = wedge[em0];
    }
#pragma unroll
    for (int o = 32; o >= 1; o >>= 1) dd += __shfl_xor(dd, o);
    if (lane == 0) Dinv[n] = (dd > 0.f) ? 1.f / dd : 0.f;

    constexpr int KMAX = (H == 4) ? 4 : 1;
    int P = deg * H;
    float vc[KMAX];
    float mx = -3.0e38f;
#pragma unroll
    for (int k = 0; k < KMAX; k++) {
      int p = lane + 64 * k;
      int idx = (H == 4) ? (p >> 2) : p;
      int em = __shfl(em0, idx);
      float v = dx + dota[em * H + h];
      v = leaky(v);
      vc[k] = v;
      if (p < P) mx = fmaxf(mx, v);
    }
#pragma unroll
    for (int o = H; o < 64; o <<= 1) mx = fmaxf(mx, __shfl_xor(mx, o));
    float sm = 0.f;
#pragma unroll
    for (int k = 0; k < KMAX; k++) {
      int p = lane + 64 * k;
      float e = __expf(vc[k] - mx);
      vc[k] = e;
      if (p < P) sm += e;
    }
#pragma unroll
    for (int o = H; o < 64; o <<= 1) sm += __shfl_xor(sm, o);
    float inv = 1.f / (sm + 1e-16f);
#pragma unroll
    for (int k = 0; k < KMAX; k++) {
      int p = lane + 64 * k;
      if (p < P) alpha[s * H + p] = vc[k] * inv;
    }
  } else {
    float dd = 0.f;
    for (int i = s + lane; i < t; i += 64) dd += wedge[em_n[i]];
#pragma unroll
    for (int o = 32; o >= 1; o >>= 1) dd += __shfl_xor(dd, o);
    if (lane == 0) Dinv[n] = (dd > 0.f) ? 1.f / dd : 0.f;
    int P = deg * H;
    float mx = -3.0e38f;
    for (int p = lane; p < P; p += 64) {
      int i = s + ((H == 4) ? (p >> 2) : p);
      float v = leaky(dx + dota[em_n[i] * H + h]);
      mx = fmaxf(mx, v);
    }
#pragma unroll
    for (int o = H; o < 64; o <<= 1) mx = fmaxf(mx, __shfl_xor(mx, o));
    float sm = 0.f;
    for (int p = lane; p < P; p += 64) {
      int i = s + ((H == 4) ? (p >> 2) : p);
      float v = leaky(dx + dota[em_n[i] * H + h]);
      sm += __expf(v - mx);
    }
#pragma unroll
    for (int o = H; o < 64; o <<= 1) sm += __shfl_xor(sm, o);
    float inv = 1.f / (sm + 1e-16f);
    for (int p = lane; p < P; p += 64) {
      int i = s + ((H == 4) ? (p >> 2) : p);
      float v = leaky(dx + dota[em_n[i] * H + h]);
      alpha[s * H + p] = __expf(v - mx) * inv;
    }
  }
}

// ---------------------------------------------------------------------------
// T[h][m][c] = sc_c * (sum alpha * raw[node,c]) + sh_c * (sum alpha)
// BN factored out of the gather loop; packed LDS stage of {rowofs, alpha}.
// 8 slots x 32 lanes, block per edge m.
// ---------------------------------------------------------------------------
template <int H>
__global__ __launch_bounds__(256) void k_T(const float4* __restrict__ h4raw,
                                           const int* __restrict__ eoff,
                                           const int2* __restrict__ npos_e,
                                           const float* __restrict__ alpha,
                                           const float* __restrict__ st,
                                           const float* __restrict__ g,
                                           const float* __restrict__ be, float ninv,
                                           float4* __restrict__ T4) {
  int m = blockIdx.x;
  int slot = threadIdx.x >> 5, c = threadIdx.x & 31;
  int wv = threadIdx.x >> 6;
  int s = eoff[m], t = eoff[m + 1];
  __shared__ int sofs[256];
  __shared__ float sal[256 * H];
  __shared__ float4 red[4][H][32];
  __shared__ float4 redA[4];
  __shared__ float sAsum[4];
  float4 acc[H];
#pragma unroll
  for (int hh = 0; hh < H; hh++) acc[hh] = make_float4(0.f, 0.f, 0.f, 0.f);
  float4 asum = make_float4(0.f, 0.f, 0.f, 0.f);

  for (int c0 = s; c0 < t; c0 += 256) {
    int cnt = min(256, t - c0);
    __syncthreads();
    if (threadIdx.x < cnt) {
      int2 np = npos_e[c0 + threadIdx.x];
      sofs[threadIdx.x] = np.x * 32;
      if (H == 4) {
        float4 a4 = ((const float4*)alpha)[np.y];
        ((float4*)sal)[threadIdx.x] = a4;
        asum = f4add(asum, a4);
      } else {
        float a = alpha[np.y];
        sal[threadIdx.x] = a;
        asum.x += a;
      }
    }
    __syncthreads();
#pragma unroll 4
    for (int j = slot; j < cnt; j += 8) {
      int ofs = sofs[j];
      float4 v = h4raw[(size_t)ofs + c];
      if (H == 4) {
        float4 a4 = ((const float4*)sal)[j];
        acc[0] = f4fma(a4.x, v, acc[0]);
        acc[1 % H] = f4fma(a4.y, v, acc[1 % H]);
        acc[2 % H] = f4fma(a4.z, v, acc[2 % H]);
        acc[3 % H] = f4fma(a4.w, v, acc[3 % H]);
      } else {
        acc[0] = f4fma(sal[j], v, acc[0]);
      }
    }
  }
#pragma unroll
  for (int hh = 0; hh < H; hh++) {
    float4 a = acc[hh];
    a.x += __shfl_xor(a.x, 32); a.y += __shfl_xor(a.y, 32);
    a.z += __shfl_xor(a.z, 32); a.w += __shfl_xor(a.w, 32);
    acc[hh] = a;
  }
#pragma unroll
  for (int o = 32; o >= 1; o >>= 1) {
    asum.x += __shfl_xor(asum.x, o); asum.y += __shfl_xor(asum.y, o);
    asum.z += __shfl_xor(asum.z, o); asum.w += __shfl_xor(asum.w, o);
  }
  if ((threadIdx.x & 63) < 32) {
#pragma unroll
    for (int hh = 0; hh < H; hh++) red[wv][hh][c] = acc[hh];
  }
  if ((threadIdx.x & 63) == 0) redA[wv] = asum;
  __syncthreads();
  if (threadIdx.x == 0) {
    float4 A = f4add(f4add(redA[0], redA[1]), f4add(redA[2], redA[3]));
    sAsum[0] = A.x; sAsum[1] = A.y; sAsum[2] = A.z; sAsum[3] = A.w;
  }
  __syncthreads();
  if (threadIdx.x < 32 * H) {
    int hh = threadIdx.x >> 5, cc = threadIdx.x & 31;
    float4 r = f4add(f4add(red[0][hh][cc], red[1][hh][cc]),
                     f4add(red[2][hh][cc], red[3][hh][cc]));
    float as = sAsum[hh];
    float4 sc, sh;
    bn_sc4(st, g, be, ninv, cc, sc, sh);
    r = make_float4(sc.x * r.x + sh.x * as, sc.y * r.y + sh.y * as,
                    sc.z * r.z + sh.z * as, sc.w * r.w + sh.w * as);
    T4[((size_t)hh * MM + m) * 32 + cc] = r;
  }
}

// ---------------------------------------------------------------------------
// out[n,c] = BN(hres)[n,c] + Dinv[n]/H * sum alpha*oute[m,h,c] + bias
// One WAVE per node, no LDS/barriers.
// ---------------------------------------------------------------------------
template <int H>
__global__ __launch_bounds__(256) void k_phase9(
    const int* __restrict__ noff, const int* __restrict__ em_n,
    const float* __restrict__ alpha, const float4* __restrict__ oute4,
    const float* __restrict__ Dinv, const float* __restrict__ bias,
    const float4* __restrict__ hres4, const float* __restrict__ st,
    const float* __restrict__ g, const float* __restrict__ be, float ninv,
    float4* __restrict__ out4) {
  int wv = threadIdx.x >> 6, lane = threadIdx.x & 63;
  int n = blockIdx.x * 4 + wv;
  int slot = lane >> 5, c = lane & 31;
  int s = noff[n], t = noff[n + 1];
  int deg = t - s;
  float4 acc = make_float4(0.f, 0.f, 0.f, 0.f);
  if (deg <= 64) {
    int m_l = 0;
    float4 a_l = make_float4(0.f, 0.f, 0.f, 0.f);
    if (lane < deg) {
      m_l = em_n[s + lane];
      if (H == 4)
        a_l = ((const float4*)alpha)[s + lane];
      else
        a_l.x = alpha[s + lane];
    }
    for (int i = slot; i < deg; i += 2) {
      int m = __shfl(m_l, i);
      if (H == 4) {
        float ax = __shfl(a_l.x, i), ay = __shfl(a_l.y, i);
        float az = __shfl(a_l.z, i), aw = __shfl(a_l.w, i);
        const float4* base = oute4 + (size_t)m * 128 + c;
        acc = f4fma(ax, base[0], acc);
        acc = f4fma(ay, base[32], acc);
        acc = f4fma(az, base[64], acc);
        acc = f4fma(aw, base[96], acc);
      } else {
        float a = __shfl(a_l.x, i);
        acc = f4fma(a, oute4[(size_t)m * 32 + c], acc);
      }
    }
  } else {
    for (int i = s + slot; i < t; i += 2) {
      int m = em_n[i];
      if (H == 4) {
        float4 a4 = ((const float4*)alpha)[i];
        const float4* base = oute4 + (size_t)m * 128 + c;
        acc = f4fma(a4.x, base[0], acc);
        acc = f4fma(a4.y, base[32], acc);
        acc = f4fma(a4.z, base[64], acc);
        acc = f4fma(a4.w, base[96], acc);
      } else {
        acc = f4fma(alpha[i], oute4[(size_t)m * 32 + c], acc);
      }
    }
  }
  acc.x += __shfl_xor(acc.x, 32); acc.y += __shfl_xor(acc.y, 32);
  acc.z += __shfl_xor(acc.z, 32); acc.w += __shfl_xor(acc.w, 32);
  if (slot == 0) {
    float scn = Dinv[n] * (1.f / H);
    float4 scB, shB;
    bn_sc4(st, g, be, ninv, c, scB, shB);
    float4 hr = hres4[(size_t)n * 32 + c];
    hr = make_float4(hr.x * scB.x + shB.x, hr.y * scB.y + shB.y, hr.z * scB.z + shB.z,
                     hr.w * scB.w + shB.w);
    float4 bi = ((const float4*)bias)[c];
    out4[(size_t)n * 32 + c] =
        make_float4(hr.x + scn * acc.x + bi.x, hr.y + scn * acc.y + bi.y,
                    hr.z + scn * acc.z + bi.z, hr.w + scn * acc.w + bi.w);
  }
}

// ---------------------------------------------------------------------------
// Host side
// ---------------------------------------------------------------------------
static inline size_t alignup(size_t x) { return (x + 255) & ~(size_t)255; }

extern "C" void kernel_launch(void* const* d_in, const int* in_sizes, int n_in,
                              void* d_out, int out_size, void* d_ws, size_t ws_size,
                              hipStream_t stream) {
  const float* x = (const float*)d_in[0];
  const int* node_idx = (const int*)d_in[1];
  const int* edge_idx = (const int*)d_in[2];
  const float* wedge = (const float*)d_in[3];
  const float* W1 = (const float*)d_in[4];
  const float* b1 = (const float*)d_in[5];
  const float* g1 = (const float*)d_in[6];
  const float* be1 = (const float*)d_in[7];
  const float* linw1 = (const float*)d_in[8];
  const float* att1 = (const float*)d_in[9];
  const float* bias1 = (const float*)d_in[10];
  const float* g2 = (const float*)d_in[11];
  const float* be2 = (const float*)d_in[12];
  const float* linw2 = (const float*)d_in[13];
  const float* att2 = (const float*)d_in[14];
  const float* bias2 = (const float*)d_in[15];
  const float* g3 = (const float*)d_in[16];
  const float* be3 = (const float*)d_in[17];
  const float* W2 = (const float*)d_in[18];
  const float* b2 = (const float*)d_in[19];
  const float* g4 = (const float*)d_in[20];
  const float* be4 = (const float*)d_in[21];
  float* out = (float*)d_out;

  char* ws = (char*)d_ws;
  size_t off = 0;
  auto alloc = [&](size_t bytes) -> void* {
    void* p = ws + off;
    off = alignup(off + bytes);
    return p;
  };
  float* buf0 = (float*)alloc((size_t)NN * 128 * 4);
  float* buf1 = (float*)alloc((size_t)NN * 128 * 4);
  float* Tbuf = (float*)alloc((size_t)4 * MM * 128 * 4);
  float* oute = (float*)alloc((size_t)MM * 4 * 128 * 4);
  float* alpha = (float*)alloc((size_t)EE * 4 * 4);
  float* dotx = (float*)alloc((size_t)NN * 4 * 4);
  float* hv = (float*)alloc((size_t)NN * 4 * 4);
  float* dota = (float*)alloc((size_t)MM * 4 * 4);
  float* UVT1 = (float*)alloc(128 * 8 * 4);
  float* UVT2 = (float*)alloc(128 * 2 * 4);
  float* Dinv = (float*)alloc((size_t)NN * 4);
  int* noff = (int*)alloc((size_t)(NN + 1) * 4);
  int* eoff = (int*)alloc((size_t)(MM + 1) * 4);
  int* em_n = (int*)alloc((size_t)EE * 4);
  int2* npos_e = (int2*)alloc((size_t)EE * 8);
  int* rank_n = (int*)alloc((size_t)EE * 4);
  int* rank_e = (int*)alloc((size_t)EE * 4);
  // zero region: cntN (8*NN), cntE (8*MM), bnst(4x256)
  size_t zero_bytes = ((size_t)NSLICE * (NN + MM) + 4 * 256) * 4;
  int* zero_region = (int*)alloc(zero_bytes);
  int* cntN = zero_region;
  int* cntE = cntN + NSLICE * NN;
  float* bnst = (float*)(cntE + NSLICE * MM);
  (void)ws_size;
  (void)in_sizes;
  (void)n_in;
  (void)out_size;

  (void)hipMemsetAsync(zero_region, 0, zero_bytes, stream);

  // CSR count (+ UVT for both layers in tail blocks)
  k_count_uv<<<NBC + 3, 256, 0, stream>>>(node_idx, edge_idx, cntN, cntE, rank_n,
                                          rank_e, linw1, att1, UVT1, linw2, att2,
                                          UVT2);
  k_scan2<<<2, 1024, 0, stream>>>(cntN, noff, cntE, eoff);
  k_fill<<<NBC * NSLICE, 256, 0, stream>>>(node_idx, edge_idx, noff, eoff, cntN, cntE,
                                           rank_n, rank_e, em_n, npos_e);

  const float ninv = 1.f / (float)NN;
  const int gemm_grid = (NN + 63) / 64;
  const int cs_grid = (NN + 255) / 256;
  const int oute_grid = (MM + 31) / 32;
  float* st0 = bnst + 0 * 256;
  float* st1 = bnst + 1 * 256;
  float* st2 = bnst + 2 * 256;
  float* st3 = bnst + 3 * 256;

  // buf0 = leaky(x@W1+b1) (raw pre-BN1), fused stats -> st0
  k_gemm128<<<gemm_grid, 256, 0, stream>>>(x, W1, b1, nullptr, nullptr, nullptr,
                                           nullptr, 0.f, buf0, st0, NN);

  // ---- hconv1 (H=4): h1 = BN1(buf0) applied inline ----
  k_dots<4><<<(NN * 8 + 255) / 256, 256, 0, stream>>>((const float4*)buf0, NN, UVT1,
                                                      st0, g1, be1, ninv, dotx, hv);
  k_dota<4><<<MM / 4, 256, 0, stream>>>(hv, eoff, npos_e, dota);
  k_softmax<4><<<NN / 4, 256, 0, stream>>>(noff, em_n, dotx, dota, wedge, alpha, Dinv);
  k_T<4><<<MM, 256, 0, stream>>>((const float4*)buf0, eoff, npos_e, alpha, st0, g1,
                                 be1, ninv, (float4*)Tbuf);
  {
    dim3 g(oute_grid, 4);
    k_oute32<4><<<g, 256, 0, stream>>>(Tbuf, linw1, eoff, wedge, oute);
  }
  k_phase9<4><<<NN / 4, 256, 0, stream>>>(noff, em_n, alpha, (const float4*)oute, Dinv,
                                          bias1, (const float4*)buf0, st0, g1, be1,
                                          ninv, (float4*)buf1);
  k_colstats<<<cs_grid, 256, 0, stream>>>((const float4*)buf1, NN, st1);

  // ---- hconv2 (H=1): h2 = BN2(buf1) applied inline ----
  k_dots<1><<<(NN * 2 + 255) / 256, 256, 0, stream>>>((const float4*)buf1, NN, UVT2,
                                                      st1, g2, be2, ninv, dotx, hv);
  k_dota<1><<<MM / 4, 256, 0, stream>>>(hv, eoff, npos_e, dota);
  k_softmax<1><<<NN / 4, 256, 0, stream>>>(noff, em_n, dotx, dota, wedge, alpha, Dinv);
  k_T<1><<<MM, 256, 0, stream>>>((const float4*)buf1, eoff, npos_e, alpha, st1, g2,
                                 be2, ninv, (float4*)Tbuf);
  {
    dim3 g(oute_grid, 1);
    k_oute32<1><<<g, 256, 0, stream>>>(Tbuf, linw2, eoff, wedge, oute);
  }
  k_phase9<1><<<NN / 4, 256, 0, stream>>>(noff, em_n, alpha, (const float4*)oute, Dinv,
                                          bias2, (const float4*)buf1, st1, g2, be2,
                                          ninv, (float4*)buf0);
  k_colstats<<<cs_grid, 256, 0, stream>>>((const float4*)buf0, NN, st2);

  // buf1 = leaky(BN3(buf0)@W2+b2) + x  (raw pre-BN4), fused stats -> st3
  k_gemm128<<<gemm_grid, 256, 0, stream>>>(buf0, W2, b2, x, st2, g3, be3, ninv, buf1,
                                           st3, NN);
  k_bnapply_final<<<(NN * 32 + 255) / 256, 256, 0, stream>>>(
      (const float4*)buf1, st3, g4, be4, ninv, (float4*)out, NN * 32);
}

// Round 8
// 335.920 us; speedup vs baseline: 1.0370x; 1.0370x over previous
//
#include <hip/hip_runtime.h>

// Problem constants (match reference)
#define NN 20000
#define MM 2000
#define EE 320000
#define NSLICE 8
#define NBC 1250  // EE/256 exactly
static constexpr float SLOPE = 0.2f;
static constexpr float EPSBN = 1e-5f;

__device__ inline float4 f4add(float4 a, float4 b) {
  return make_float4(a.x + b.x, a.y + b.y, a.z + b.z, a.w + b.w);
}
__device__ inline float4 f4fma(float a, float4 v, float4 c) {
  return make_float4(c.x + a * v.x, c.y + a * v.y, c.z + a * v.z, c.w + a * v.w);
}
__device__ inline float leaky(float v) { return (v > 0.f) ? v : SLOPE * v; }

// per-thread BN scale/shift for 4 channels (f4 index c4)
__device__ inline void bn_sc4(const float* __restrict__ st, const float* __restrict__ g,
                              const float* __restrict__ be, float ninv, int c4,
                              float4& sc, float4& sh) {
  float* scp = &sc.x;
  float* shp = &sh.x;
#pragma unroll
  for (int j = 0; j < 4; j++) {
    int c = c4 * 4 + j;
    float mu = st[c] * ninv;
    float var = st[128 + c] * ninv - mu * mu;
    float s = g[c] * rsqrtf(var + EPSBN);
    scp[j] = s;
    shp[j] = be[c] - mu * s;
  }
}

// ---------------------------------------------------------------------------
// CSR count (XCD-sliced counters) + both layers' UVT folded into tail blocks.
// ---------------------------------------------------------------------------
__global__ void k_count_uv(const int* __restrict__ ni, const int* __restrict__ ei,
                           int* cntN, int* cntE, int* __restrict__ rank_n,
                           int* __restrict__ rank_e, const float* __restrict__ linw1,
                           const float* __restrict__ att1, float* __restrict__ UVT1,
                           const float* __restrict__ linw2,
                           const float* __restrict__ att2, float* __restrict__ UVT2) {
  int b = blockIdx.x;
  if (b < NBC) {
    int e = b * 256 + threadIdx.x;
    int s = b & (NSLICE - 1);
    rank_n[e] = atomicAdd(&cntN[s * NN + ni[e]], 1);
    rank_e[e] = atomicAdd(&cntE[s * MM + ei[e]], 1);
  } else if (b < NBC + 2) {
    constexpr int H = 4;
    int idx = (b - NBC) * 256 + threadIdx.x;
    int h = idx >> 7, k = idx & 127;
    float u = 0.f, v = 0.f;
    for (int c = 0; c < 128; c++) {
      float w = linw1[(size_t)k * (128 * H) + h * 128 + c];
      u += w * att1[h * 256 + c];
      v += w * att1[h * 256 + 128 + c];
    }
    UVT1[h * 128 + k] = u;
    UVT1[(H + h) * 128 + k] = v;
  } else {
    if (threadIdx.x >= 128) return;
    int k = threadIdx.x;
    float u = 0.f, v = 0.f;
    for (int c = 0; c < 128; c++) {
      float w = linw2[(size_t)k * 128 + c];
      u += w * att2[c];
      v += w * att2[128 + c];
    }
    UVT2[k] = u;
    UVT2[128 + k] = v;
  }
}

// per-key exclusive scan over the 8 slices (parallel across keys);
// cnt[s][key] becomes within-key slice base, tot[key] = total.
__global__ void k_slicescan(int* __restrict__ cntN, int* __restrict__ totN,
                            int* __restrict__ cntE, int* __restrict__ totE) {
  int i = blockIdx.x * 256 + threadIdx.x;
  if (i < NN) {
    int run = 0;
#pragma unroll
    for (int s = 0; s < NSLICE; s++) {
      int t = cntN[s * NN + i];
      cntN[s * NN + i] = run;
      run += t;
    }
    totN[i] = run;
  } else if (i < NN + MM) {
    int m = i - NN;
    int run = 0;
#pragma unroll
    for (int s = 0; s < NSLICE; s++) {
      int t = cntE[s * MM + m];
      cntE[s * MM + m] = run;
      run += t;
    }
    totE[m] = run;
  }
}

// dual single-block exclusive scan (block 0: nodes, block 1: edges)
__global__ __launch_bounds__(1024) void k_scan2(const int* __restrict__ totN,
                                                int* __restrict__ noff,
                                                const int* __restrict__ totE,
                                                int* __restrict__ eoff) {
  const int* cnt = blockIdx.x ? totE : totN;
  int* off = blockIdx.x ? eoff : noff;
  int n = blockIdx.x ? MM : NN;
  __shared__ int swav[16];
  __shared__ int sCarry;
  int t = threadIdx.x;
  int lane = t & 63, wid = t >> 6;
  if (t == 0) sCarry = 0;
  __syncthreads();
  for (int base = 0; base < n; base += 1024) {
    int i = base + t;
    int v = (i < n) ? cnt[i] : 0;
    int x = v;
#pragma unroll
    for (int o = 1; o < 64; o <<= 1) {
      int y = __shfl_up(x, o);
      if (lane >= o) x += y;
    }
    if (lane == 63) swav[wid] = x;
    __syncthreads();
    if (wid == 0) {
      int s = (lane < 16) ? swav[lane] : 0;
#pragma unroll
      for (int o = 1; o < 16; o <<= 1) {
        int y = __shfl_up(s, o);
        if (lane >= o) s += y;
      }
      if (lane < 16) swav[lane] = s;
    }
    __syncthreads();
    int wpre = wid ? swav[wid - 1] : 0;
    int total = swav[15];
    if (i < n) off[i] = sCarry + wpre + x - v;
    __syncthreads();
    if (t == 0) sCarry += total;
    __syncthreads();
  }
  if (t == 0) off[n] = sCarry;
}

// ---------------------------------------------------------------------------
// Atomic-free fill, XCD-partitioned WRITES: 8 blocks visit each chunk; block
// with slice s writes only destinations in [s*EE/8, (s+1)*EE/8) so every
// 64B line of em_n / npos_e is written from a single XCD's L2.
// ---------------------------------------------------------------------------
__global__ void k_fill(const int* __restrict__ ni, const int* __restrict__ ei,
                       const int* __restrict__ noff, const int* __restrict__ eoff,
                       const int* __restrict__ cntN, const int* __restrict__ cntE,
                       const int* __restrict__ rank_n, const int* __restrict__ rank_e,
                       int* __restrict__ em_n, int2* __restrict__ npos_e) {
  int chunk = blockIdx.x >> 3;
  int s = blockIdx.x & (NSLICE - 1);
  int e = chunk * 256 + threadIdx.x;
  int so = chunk & (NSLICE - 1);  // slice used by k_count for this chunk
  int n = ni[e];
  int m = ei[e];
  int pn = noff[n] + cntN[so * NN + n] + rank_n[e];
  int pe = eoff[m] + cntE[so * MM + m] + rank_e[e];
  const int SH = EE / NSLICE;  // 40000
  if (pn / SH == s) em_n[pn] = m;
  if (pe / SH == s) npos_e[pe] = make_int2(n, pn);
}

// ---------------------------------------------------------------------------
// Tiled GEMM: out = maybe_resid + leaky(BNopt(A)[rows,128] @ W[128,128] + b)
// Fused column stats (sum,sumsq) of the OUTPUT -> atomicAdd into stout.
// ---------------------------------------------------------------------------
__global__ __launch_bounds__(256) void k_gemm128(
    const float* __restrict__ A, const float* __restrict__ W,
    const float* __restrict__ bias, const float* __restrict__ resid,
    const float* __restrict__ st, const float* __restrict__ g,
    const float* __restrict__ be, float ninv, float* __restrict__ out,
    float* __restrict__ stout, int rows) {
  __shared__ float As[32][68];
  __shared__ float Ws[32][132];
  __shared__ float scs[128], shs[128];
  if (st && threadIdx.x < 128) {
    int c = threadIdx.x;
    float mu = st[c] * ninv;
    float var = st[128 + c] * ninv - mu * mu;
    float s = g[c] * rsqrtf(var + EPSBN);
    scs[c] = s;
    shs[c] = be[c] - mu * s;
  }
  if (st) __syncthreads();
  int tx = threadIdx.x & 15, ty = threadIdx.x >> 4;
  int r0 = blockIdx.x * 64;
  float4 acc[4][2];
#pragma unroll
  for (int j = 0; j < 4; j++) acc[j][0] = acc[j][1] = make_float4(0.f, 0.f, 0.f, 0.f);

  for (int k0 = 0; k0 < 128; k0 += 32) {
    __syncthreads();
    {
      int row = threadIdx.x >> 2, kq = threadIdx.x & 3;
      int rr = r0 + row;
      float4 a0 = make_float4(0.f, 0.f, 0.f, 0.f), a1 = a0;
      if (rr < rows) {
        const float* ap = A + (size_t)rr * 128 + k0 + kq * 8;
        a0 = ((const float4*)ap)[0];
        a1 = ((const float4*)ap)[1];
      }
      int kb = k0 + kq * 8;
      if (st) {
        a0.x = a0.x * scs[kb + 0] + shs[kb + 0];
        a0.y = a0.y * scs[kb + 1] + shs[kb + 1];
        a0.z = a0.z * scs[kb + 2] + shs[kb + 2];
        a0.w = a0.w * scs[kb + 3] + shs[kb + 3];
        a1.x = a1.x * scs[kb + 4] + shs[kb + 4];
        a1.y = a1.y * scs[kb + 5] + shs[kb + 5];
        a1.z = a1.z * scs[kb + 6] + shs[kb + 6];
        a1.w = a1.w * scs[kb + 7] + shs[kb + 7];
      }
      int kl = kq * 8;
      As[kl + 0][row] = a0.x;
      As[kl + 1][row] = a0.y;
      As[kl + 2][row] = a0.z;
      As[kl + 3][row] = a0.w;
      As[kl + 4][row] = a1.x;
      As[kl + 5][row] = a1.y;
      As[kl + 6][row] = a1.z;
      As[kl + 7][row] = a1.w;
    }
    {
      int kk = threadIdx.x >> 3, cq = threadIdx.x & 7;
      const float* wp = W + (size_t)(k0 + kk) * 128 + cq * 16;
#pragma unroll
      for (int f = 0; f < 4; f++)
        *(float4*)&Ws[kk][cq * 16 + f * 4] = ((const float4*)wp)[f];
    }
    __syncthreads();
#pragma unroll
    for (int kk = 0; kk < 32; kk++) {
      float4 a = *(const float4*)&As[kk][ty * 4];
      float4 w0 = *(const float4*)&Ws[kk][tx * 8];
      float4 w1 = *(const float4*)&Ws[kk][tx * 8 + 4];
      acc[0][0] = f4fma(a.x, w0, acc[0][0]);
      acc[0][1] = f4fma(a.x, w1, acc[0][1]);
      acc[1][0] = f4fma(a.y, w0, acc[1][0]);
      acc[1][1] = f4fma(a.y, w1, acc[1][1]);
      acc[2][0] = f4fma(a.z, w0, acc[2][0]);
      acc[2][1] = f4fma(a.z, w1, acc[2][1]);
      acc[3][0] = f4fma(a.w, w0, acc[3][0]);
      acc[3][1] = f4fma(a.w, w1, acc[3][1]);
    }
  }
  float4 b0 = ((const float4*)bias)[tx * 2];
  float4 b1 = ((const float4*)bias)[tx * 2 + 1];
  float4 cs0 = make_float4(0.f, 0.f, 0.f, 0.f), cs1 = cs0, cq0 = cs0, cq1 = cs0;
#pragma unroll
  for (int j = 0; j < 4; j++) {
    int r = r0 + ty * 4 + j;
    if (r < rows) {
      float4 o0 = acc[j][0], o1 = acc[j][1];
      o0 = make_float4(leaky(o0.x + b0.x), leaky(o0.y + b0.y), leaky(o0.z + b0.z),
                       leaky(o0.w + b0.w));
      o1 = make_float4(leaky(o1.x + b1.x), leaky(o1.y + b1.y), leaky(o1.z + b1.z),
                       leaky(o1.w + b1.w));
      if (resid) {
        float4 r0v = ((const float4*)resid)[(size_t)r * 32 + tx * 2];
        float4 r1v = ((const float4*)resid)[(size_t)r * 32 + tx * 2 + 1];
        o0 = f4add(o0, r0v);
        o1 = f4add(o1, r1v);
      }
      ((float4*)out)[(size_t)r * 32 + tx * 2] = o0;
      ((float4*)out)[(size_t)r * 32 + tx * 2 + 1] = o1;
      cs0 = f4add(cs0, o0);
      cs1 = f4add(cs1, o1);
      cq0 = make_float4(cq0.x + o0.x * o0.x, cq0.y + o0.y * o0.y, cq0.z + o0.z * o0.z,
                        cq0.w + o0.w * o0.w);
      cq1 = make_float4(cq1.x + o1.x * o1.x, cq1.y + o1.y * o1.y, cq1.z + o1.z * o1.z,
                        cq1.w + o1.w * o1.w);
    }
  }
  // fused column stats: reuse As (sum) / Ws (sumsq) LDS as [16][128]
  __syncthreads();
  float* sumb = &As[0][0];
  float* sqb = &Ws[0][0];
  *(float4*)&sumb[ty * 128 + tx * 8] = cs0;
  *(float4*)&sumb[ty * 128 + tx * 8 + 4] = cs1;
  *(float4*)&sqb[ty * 128 + tx * 8] = cq0;
  *(float4*)&sqb[ty * 128 + tx * 8 + 4] = cq1;
  __syncthreads();
  if (threadIdx.x < 128) {
    float S = 0.f, Q = 0.f;
#pragma unroll
    for (int w = 0; w < 16; w++) {
      S += sumb[w * 128 + threadIdx.x];
      Q += sqb[w * 128 + threadIdx.x];
    }
    atomicAdd(&stout[threadIdx.x], S);
    atomicAdd(&stout[128 + threadIdx.x], Q);
  }
}

// ---------------------------------------------------------------------------
// out_e[m][h][c] = (wedge[m]/deg) * (T[h][m][:] @ lin_w[:, h*128 + c])
// 32-row tiles for occupancy (grid (63,H)).
// ---------------------------------------------------------------------------
template <int H>
__global__ __launch_bounds__(256) void k_oute32(const float* __restrict__ T,
                                                const float* __restrict__ linw,
                                                const int* __restrict__ eoff,
                                                const float* __restrict__ wedge,
                                                float* __restrict__ oute) {
  int h = blockIdx.y;
  __shared__ float As[32][36];   // [k][row], 32 rows
  __shared__ float Ws[32][132];  // [k][col]
  int tx = threadIdx.x & 15, ty = threadIdx.x >> 4;
  int r0 = blockIdx.x * 32;
  const float* A = T + (size_t)h * MM * 128;
  float4 acc[2][2];
#pragma unroll
  for (int j = 0; j < 2; j++) acc[j][0] = acc[j][1] = make_float4(0.f, 0.f, 0.f, 0.f);

  for (int k0 = 0; k0 < 128; k0 += 32) {
    __syncthreads();
    {
      int row = threadIdx.x >> 3, kq = threadIdx.x & 7;
      int rr = r0 + row;
      float4 a0 = make_float4(0.f, 0.f, 0.f, 0.f);
      if (rr < MM) a0 = *(const float4*)(A + (size_t)rr * 128 + k0 + kq * 4);
      int kb = kq * 4;
      As[kb + 0][row] = a0.x;
      As[kb + 1][row] = a0.y;
      As[kb + 2][row] = a0.z;
      As[kb + 3][row] = a0.w;
    }
    {
      int kk = threadIdx.x >> 3, cq = threadIdx.x & 7;
      const float* wp = linw + (size_t)(k0 + kk) * (128 * H) + h * 128 + cq * 16;
#pragma unroll
      for (int f = 0; f < 4; f++)
        *(float4*)&Ws[kk][cq * 16 + f * 4] = ((const float4*)wp)[f];
    }
    __syncthreads();
#pragma unroll
    for (int kk = 0; kk < 32; kk++) {
      float a0 = As[kk][ty * 2], a1 = As[kk][ty * 2 + 1];
      float4 w0 = *(const float4*)&Ws[kk][tx * 8];
      float4 w1 = *(const float4*)&Ws[kk][tx * 8 + 4];
      acc[0][0] = f4fma(a0, w0, acc[0][0]);
      acc[0][1] = f4fma(a0, w1, acc[0][1]);
      acc[1][0] = f4fma(a1, w0, acc[1][0]);
      acc[1][1] = f4fma(a1, w1, acc[1][1]);
    }
  }
#pragma unroll
  for (int j = 0; j < 2; j++) {
    int m = r0 + ty * 2 + j;
    if (m >= MM) break;
    int d = eoff[m + 1] - eoff[m];
    float bv = (d > 0) ? wedge[m] / (float)d : 0.f;
    float4 o0 = acc[j][0], o1 = acc[j][1];
    o0 = make_float4(bv * o0.x, bv * o0.y, bv * o0.z, bv * o0.w);
    o1 = make_float4(bv * o1.x, bv * o1.y, bv * o1.z, bv * o1.w);
    ((float4*)oute)[((size_t)m * H + h) * 32 + tx * 2] = o0;
    ((float4*)oute)[((size_t)m * H + h) * 32 + tx * 2 + 1] = o1;
  }
}

// ---------------------------------------------------------------------------
// BatchNorm column stats (sum, sumsq) -- standalone (for phase9 outputs)
// ---------------------------------------------------------------------------
__global__ __launch_bounds__(256) void k_colstats(const float4* __restrict__ X4,
                                                  int rows, float* __restrict__ st) {
  int c4 = threadIdx.x & 31, rs = threadIdx.x >> 5, wid = threadIdx.x >> 6;
  int r0 = blockIdx.x * 256;
  int rend = min(r0 + 256, rows);
  float4 s = make_float4(0.f, 0.f, 0.f, 0.f), q = s;
  for (int r = r0 + rs; r < rend; r += 8) {
    float4 v = X4[(size_t)r * 32 + c4];
    s = f4add(s, v);
    q = make_float4(q.x + v.x * v.x, q.y + v.y * v.y, q.z + v.z * v.z, q.w + v.w * v.w);
  }
  s.x += __shfl_xor(s.x, 32); s.y += __shfl_xor(s.y, 32);
  s.z += __shfl_xor(s.z, 32); s.w += __shfl_xor(s.w, 32);
  q.x += __shfl_xor(q.x, 32); q.y += __shfl_xor(q.y, 32);
  q.z += __shfl_xor(q.z, 32); q.w += __shfl_xor(q.w, 32);
  __shared__ float4 red[4][32][2];
  if ((threadIdx.x & 63) < 32) {
    red[wid][c4][0] = s;
    red[wid][c4][1] = q;
  }
  __syncthreads();
  if (threadIdx.x < 32) {
    float4 S = f4add(f4add(red[0][threadIdx.x][0], red[1][threadIdx.x][0]),
                     f4add(red[2][threadIdx.x][0], red[3][threadIdx.x][0]));
    float4 Q = f4add(f4add(red[0][threadIdx.x][1], red[1][threadIdx.x][1]),
                     f4add(red[2][threadIdx.x][1], red[3][threadIdx.x][1]));
    int c = threadIdx.x * 4;
    atomicAdd(&st[c + 0], S.x);
    atomicAdd(&st[c + 1], S.y);
    atomicAdd(&st[c + 2], S.z);
    atomicAdd(&st[c + 3], S.w);
    atomicAdd(&st[128 + c + 0], Q.x);
    atomicAdd(&st[128 + c + 1], Q.y);
    atomicAdd(&st[128 + c + 2], Q.z);
    atomicAdd(&st[128 + c + 3], Q.w);
  }
}

// final: out = BN(X) computed from raw stats
__global__ void k_bnapply_final(const float4* __restrict__ X4,
                                const float* __restrict__ st,
                                const float* __restrict__ g,
                                const float* __restrict__ be, float ninv,
                                float4* __restrict__ Y4, int total4) {
  int i = blockIdx.x * 256 + threadIdx.x;
  if (i >= total4) return;
  int c4 = i & 31;
  float4 sc, sh;
  bn_sc4(st, g, be, ninv, c4, sc, sh);
  float4 v = X4[i];
  Y4[i] = make_float4(v.x * sc.x + sh.x, v.y * sc.y + sh.y, v.z * sc.z + sh.z,
                      v.w * sc.w + sh.w);
}

// ---------------------------------------------------------------------------
// Row-per-thread dots: one thread reads BN(X)[n,:] once and computes all 2H
// dot products (U then V). Ut reads are wave-uniform -> LDS broadcast (free).
// ---------------------------------------------------------------------------
template <int H>
__global__ void k_dots(const float4* __restrict__ X4, int rows,
                       const float* __restrict__ UVT, const float* __restrict__ st,
                       const float* __restrict__ g, const float* __restrict__ be,
                       float ninv, float* __restrict__ dotx, float* __restrict__ hv) {
  __shared__ float4 Ut[2 * H * 32];
  __shared__ float4 scl[32], shl[32];
  if (threadIdx.x < 32) {
    float4 sc, sh;
    bn_sc4(st, g, be, ninv, threadIdx.x, sc, sh);
    scl[threadIdx.x] = sc;
    shl[threadIdx.x] = sh;
  }
  for (int i = threadIdx.x; i < 2 * H * 32; i += 256) Ut[i] = ((const float4*)UVT)[i];
  __syncthreads();
  int n = blockIdx.x * 256 + threadIdx.x;
  if (n >= rows) return;
  const float4* xr = X4 + (size_t)n * 32;
  float acc[2 * H];
#pragma unroll
  for (int h2 = 0; h2 < 2 * H; h2++) acc[h2] = 0.f;
#pragma unroll 4
  for (int q = 0; q < 32; q++) {
    float4 a = xr[q], c = scl[q], d = shl[q];
    float ax = a.x * c.x + d.x, ay = a.y * c.y + d.y;
    float az = a.z * c.z + d.z, aw = a.w * c.w + d.w;
#pragma unroll
    for (int h2 = 0; h2 < 2 * H; h2++) {
      float4 b = Ut[h2 * 32 + q];
      acc[h2] += ax * b.x + ay * b.y + az * b.z + aw * b.w;
    }
  }
#pragma unroll
  for (int h = 0; h < H; h++) dotx[n * H + h] = acc[h];
#pragma unroll
  for (int h = 0; h < H; h++) hv[n * H + h] = acc[H + h];
}

// dota[m,h] = sum over incidences of edge m of hv[node, h]
template <int H>
__global__ void k_dota(const float* __restrict__ hv, const int* __restrict__ eoff,
                       const int2* __restrict__ npos_e, float* __restrict__ dota) {
  int lane = threadIdx.x & 63;
  int m = blockIdx.x * 4 + (threadIdx.x >> 6);
  int s = eoff[m], t = eoff[m + 1];
  if (H == 4) {
    float4 acc = make_float4(0.f, 0.f, 0.f, 0.f);
    const float4* hv4 = (const float4*)hv;
    for (int j = s + lane; j < t; j += 64) acc = f4add(acc, hv4[npos_e[j].x]);
#pragma unroll
    for (int o = 32; o >= 1; o >>= 1) {
      acc.x += __shfl_xor(acc.x, o);
      acc.y += __shfl_xor(acc.y, o);
      acc.z += __shfl_xor(acc.z, o);
      acc.w += __shfl_xor(acc.w, o);
    }
    if (lane == 0) ((float4*)dota)[m] = acc;
  } else {
    float acc = 0.f;
    for (int j = s + lane; j < t; j += 64) acc += hv[npos_e[j].x];
#pragma unroll
    for (int o = 32; o >= 1; o >>= 1) acc += __shfl_xor(acc, o);
    if (lane == 0) dota[m] = acc;
  }
}

// ---------------------------------------------------------------------------
// Per-node segment softmax; alpha stored in node-CSR order.
// ---------------------------------------------------------------------------
template <int H>
__global__ void k_softmax(const int* __restrict__ noff, const int* __restrict__ em_n,
                          const float* __restrict__ dotx, const float* __restrict__ dota,
                          const float* __restrict__ wedge, float* __restrict__ alpha,
                          float* __restrict__ Dinv) {
  int lane = threadIdx.x & 63;
  int n = blockIdx.x * 4 + (threadIdx.x >> 6);
  int s = noff[n], t = noff[n + 1];
  int deg = t - s;
  int h = lane & (H - 1);
  float dx = dotx[n * H + h];
  if (deg <= 64) {
    int em0 = 0;
    float dd = 0.f;
    if (lane < deg) {
      em0 = em_n[s + lane];
      dd = wedge[em0];
    }
#pragma unroll
    for (int o = 32; o >= 1; o >>= 1) dd += __shfl_xor(dd, o);
    if (lane == 0) Dinv[n] = (dd > 0.f) ? 1.f / dd : 0.f;

    constexpr int KMAX = (H == 4) ? 4 : 1;
    int P = deg * H;
    float vc[KMAX];
    float mx = -3.0e38f;
#pragma unroll
    for (int k = 0; k < KMAX; k++) {
      int p = lane + 64 * k;
      int idx = (H == 4) ? (p >> 2) : p;
      int em = __shfl(em0, idx);
      float v = dx + dota[em * H + h];
      v = leaky(v);
      vc[k] = v;
      if (p < P) mx = fmaxf(mx, v);
    }
#pragma unroll
    for (int o = H; o < 64; o <<= 1) mx = fmaxf(mx, __shfl_xor(mx, o));
    float sm = 0.f;
#pragma unroll
    for (int k = 0; k < KMAX; k++) {
      int p = lane + 64 * k;
      float e = __expf(vc[k] - mx);
      vc[k] = e;
      if (p < P) sm += e;
    }
#pragma unroll
    for (int o = H; o < 64; o <<= 1) sm += __shfl_xor(sm, o);
    float inv = 1.f / (sm + 1e-16f);
#pragma unroll
    for (int k = 0; k < KMAX; k++) {
      int p = lane + 64 * k;
      if (p < P) alpha[s * H + p] = vc[k] * inv;
    }
  } else {
    float dd = 0.f;
    for (int i = s + lane; i < t; i += 64) dd += wedge[em_n[i]];
#pragma unroll
    for (int o = 32; o >= 1; o >>= 1) dd += __shfl_xor(dd, o);
    if (lane == 0) Dinv[n] = (dd > 0.f) ? 1.f / dd : 0.f;
    int P = deg * H;
    float mx = -3.0e38f;
    for (int p = lane; p < P; p += 64) {
      int i = s + ((H == 4) ? (p >> 2) : p);
      float v = leaky(dx + dota[em_n[i] * H + h]);
      mx = fmaxf(mx, v);
    }
#pragma unroll
    for (int o = H; o < 64; o <<= 1) mx = fmaxf(mx, __shfl_xor(mx, o));
    float sm = 0.f;
    for (int p = lane; p < P; p += 64) {
      int i = s + ((H == 4) ? (p >> 2) : p);
      float v = leaky(dx + dota[em_n[i] * H + h]);
      sm += __expf(v - mx);
    }
#pragma unroll
    for (int o = H; o < 64; o <<= 1) sm += __shfl_xor(sm, o);
    float inv = 1.f / (sm + 1e-16f);
    for (int p = lane; p < P; p += 64) {
      int i = s + ((H == 4) ? (p >> 2) : p);
      float v = leaky(dx + dota[em_n[i] * H + h]);
      alpha[s * H + p] = __expf(v - mx) * inv;
    }
  }
}

// ---------------------------------------------------------------------------
// T[h][m][c] = sc_c * (sum alpha * raw[node,c]) + sh_c * (sum alpha)
// BN factored out of the gather loop; packed LDS stage of {rowofs, alpha}.
// 8 slots x 32 lanes, block per edge m.
// ---------------------------------------------------------------------------
template <int H>
__global__ __launch_bounds__(256) void k_T(const float4* __restrict__ h4raw,
                                           const int* __restrict__ eoff,
                                           const int2* __restrict__ npos_e,
                                           const float* __restrict__ alpha,
                                           const float* __restrict__ st,
                                           const float* __restrict__ g,
                                           const float* __restrict__ be, float ninv,
                                           float4* __restrict__ T4) {
  int m = blockIdx.x;
  int slot = threadIdx.x >> 5, c = threadIdx.x & 31;
  int wv = threadIdx.x >> 6;
  int s = eoff[m], t = eoff[m + 1];
  __shared__ int sofs[256];
  __shared__ float sal[256 * H];
  __shared__ float4 red[4][H][32];
  __shared__ float4 redA[4];
  __shared__ float sAsum[4];
  float4 acc[H];
#pragma unroll
  for (int hh = 0; hh < H; hh++) acc[hh] = make_float4(0.f, 0.f, 0.f, 0.f);
  float4 asum = make_float4(0.f, 0.f, 0.f, 0.f);

  for (int c0 = s; c0 < t; c0 += 256) {
    int cnt = min(256, t - c0);
    __syncthreads();
    if (threadIdx.x < cnt) {
      int2 np = npos_e[c0 + threadIdx.x];
      sofs[threadIdx.x] = np.x * 32;
      if (H == 4) {
        float4 a4 = ((const float4*)alpha)[np.y];
        ((float4*)sal)[threadIdx.x] = a4;
        asum = f4add(asum, a4);
      } else {
        float a = alpha[np.y];
        sal[threadIdx.x] = a;
        asum.x += a;
      }
    }
    __syncthreads();
#pragma unroll 4
    for (int j = slot; j < cnt; j += 8) {
      int ofs = sofs[j];
      float4 v = h4raw[(size_t)ofs + c];
      if (H == 4) {
        float4 a4 = ((const float4*)sal)[j];
        acc[0] = f4fma(a4.x, v, acc[0]);
        acc[1 % H] = f4fma(a4.y, v, acc[1 % H]);
        acc[2 % H] = f4fma(a4.z, v, acc[2 % H]);
        acc[3 % H] = f4fma(a4.w, v, acc[3 % H]);
      } else {
        acc[0] = f4fma(sal[j], v, acc[0]);
      }
    }
  }
#pragma unroll
  for (int hh = 0; hh < H; hh++) {
    float4 a = acc[hh];
    a.x += __shfl_xor(a.x, 32); a.y += __shfl_xor(a.y, 32);
    a.z += __shfl_xor(a.z, 32); a.w += __shfl_xor(a.w, 32);
    acc[hh] = a;
  }
#pragma unroll
  for (int o = 32; o >= 1; o >>= 1) {
    asum.x += __shfl_xor(asum.x, o); asum.y += __shfl_xor(asum.y, o);
    asum.z += __shfl_xor(asum.z, o); asum.w += __shfl_xor(asum.w, o);
  }
  if ((threadIdx.x & 63) < 32) {
#pragma unroll
    for (int hh = 0; hh < H; hh++) red[wv][hh][c] = acc[hh];
  }
  if ((threadIdx.x & 63) == 0) redA[wv] = asum;
  __syncthreads();
  if (threadIdx.x == 0) {
    float4 A = f4add(f4add(redA[0], redA[1]), f4add(redA[2], redA[3]));
    sAsum[0] = A.x; sAsum[1] = A.y; sAsum[2] = A.z; sAsum[3] = A.w;
  }
  __syncthreads();
  if (threadIdx.x < 32 * H) {
    int hh = threadIdx.x >> 5, cc = threadIdx.x & 31;
    float4 r = f4add(f4add(red[0][hh][cc], red[1][hh][cc]),
                     f4add(red[2][hh][cc], red[3][hh][cc]));
    float as = sAsum[hh];
    float4 sc, sh;
    bn_sc4(st, g, be, ninv, cc, sc, sh);
    r = make_float4(sc.x * r.x + sh.x * as, sc.y * r.y + sh.y * as,
                    sc.z * r.z + sh.z * as, sc.w * r.w + sh.w * as);
    T4[((size_t)hh * MM + m) * 32 + cc] = r;
  }
}

// ---------------------------------------------------------------------------
// out[n,c] = BN(hres)[n,c] + Dinv[n]/H * sum alpha*oute[m,h,c] + bias
// One WAVE per node, no LDS/barriers.
// ---------------------------------------------------------------------------
template <int H>
__global__ __launch_bounds__(256) void k_phase9(
    const int* __restrict__ noff, const int* __restrict__ em_n,
    const float* __restrict__ alpha, const float4* __restrict__ oute4,
    const float* __restrict__ Dinv, const float* __restrict__ bias,
    const float4* __restrict__ hres4, const float* __restrict__ st,
    const float* __restrict__ g, const float* __restrict__ be, float ninv,
    float4* __restrict__ out4) {
  int wv = threadIdx.x >> 6, lane = threadIdx.x & 63;
  int n = blockIdx.x * 4 + wv;
  int slot = lane >> 5, c = lane & 31;
  int s = noff[n], t = noff[n + 1];
  int deg = t - s;
  float4 acc = make_float4(0.f, 0.f, 0.f, 0.f);
  if (deg <= 64) {
    int m_l = 0;
    float4 a_l = make_float4(0.f, 0.f, 0.f, 0.f);
    if (lane < deg) {
      m_l = em_n[s + lane];
      if (H == 4)
        a_l = ((const float4*)alpha)[s + lane];
      else
        a_l.x = alpha[s + lane];
    }
    for (int i = slot; i < deg; i += 2) {
      int m = __shfl(m_l, i);
      if (H == 4) {
        float ax = __shfl(a_l.x, i), ay = __shfl(a_l.y, i);
        float az = __shfl(a_l.z, i), aw = __shfl(a_l.w, i);
        const float4* base = oute4 + (size_t)m * 128 + c;
        acc = f4fma(ax, base[0], acc);
        acc = f4fma(ay, base[32], acc);
        acc = f4fma(az, base[64], acc);
        acc = f4fma(aw, base[96], acc);
      } else {
        float a = __shfl(a_l.x, i);
        acc = f4fma(a, oute4[(size_t)m * 32 + c], acc);
      }
    }
  } else {
    for (int i = s + slot; i < t; i += 2) {
      int m = em_n[i];
      if (H == 4) {
        float4 a4 = ((const float4*)alpha)[i];
        const float4* base = oute4 + (size_t)m * 128 + c;
        acc = f4fma(a4.x, base[0], acc);
        acc = f4fma(a4.y, base[32], acc);
        acc = f4fma(a4.z, base[64], acc);
        acc = f4fma(a4.w, base[96], acc);
      } else {
        acc = f4fma(alpha[i], oute4[(size_t)m * 32 + c], acc);
      }
    }
  }
  acc.x += __shfl_xor(acc.x, 32); acc.y += __shfl_xor(acc.y, 32);
  acc.z += __shfl_xor(acc.z, 32); acc.w += __shfl_xor(acc.w, 32);
  if (slot == 0) {
    float scn = Dinv[n] * (1.f / H);
    float4 scB, shB;
    bn_sc4(st, g, be, ninv, c, scB, shB);
    float4 hr = hres4[(size_t)n * 32 + c];
    hr = make_float4(hr.x * scB.x + shB.x, hr.y * scB.y + shB.y, hr.z * scB.z + shB.z,
                     hr.w * scB.w + shB.w);
    float4 bi = ((const float4*)bias)[c];
    out4[(size_t)n * 32 + c] =
        make_float4(hr.x + scn * acc.x + bi.x, hr.y + scn * acc.y + bi.y,
                    hr.z + scn * acc.z + bi.z, hr.w + scn * acc.w + bi.w);
  }
}

// ---------------------------------------------------------------------------
// Host side
// ---------------------------------------------------------------------------
static inline size_t alignup(size_t x) { return (x + 255) & ~(size_t)255; }

extern "C" void kernel_launch(void* const* d_in, const int* in_sizes, int n_in,
                              void* d_out, int out_size, void* d_ws, size_t ws_size,
                              hipStream_t stream) {
  const float* x = (const float*)d_in[0];
  const int* node_idx = (const int*)d_in[1];
  const int* edge_idx = (const int*)d_in[2];
  const float* wedge = (const float*)d_in[3];
  const float* W1 = (const float*)d_in[4];
  const float* b1 = (const float*)d_in[5];
  const float* g1 = (const float*)d_in[6];
  const float* be1 = (const float*)d_in[7];
  const float* linw1 = (const float*)d_in[8];
  const float* att1 = (const float*)d_in[9];
  const float* bias1 = (const float*)d_in[10];
  const float* g2 = (const float*)d_in[11];
  const float* be2 = (const float*)d_in[12];
  const float* linw2 = (const float*)d_in[13];
  const float* att2 = (const float*)d_in[14];
  const float* bias2 = (const float*)d_in[15];
  const float* g3 = (const float*)d_in[16];
  const float* be3 = (const float*)d_in[17];
  const float* W2 = (const float*)d_in[18];
  const float* b2 = (const float*)d_in[19];
  const float* g4 = (const float*)d_in[20];
  const float* be4 = (const float*)d_in[21];
  float* out = (float*)d_out;

  char* ws = (char*)d_ws;
  size_t off = 0;
  auto alloc = [&](size_t bytes) -> void* {
    void* p = ws + off;
    off = alignup(off + bytes);
    return p;
  };
  float* buf0 = (float*)alloc((size_t)NN * 128 * 4);
  float* buf1 = (float*)alloc((size_t)NN * 128 * 4);
  float* Tbuf = (float*)alloc((size_t)4 * MM * 128 * 4);
  float* oute = (float*)alloc((size_t)MM * 4 * 128 * 4);
  float* alpha = (float*)alloc((size_t)EE * 4 * 4);
  float* dotx = (float*)alloc((size_t)NN * 4 * 4);
  float* hv = (float*)alloc((size_t)NN * 4 * 4);
  float* dota = (float*)alloc((size_t)MM * 4 * 4);
  float* UVT1 = (float*)alloc(128 * 8 * 4);
  float* UVT2 = (float*)alloc(128 * 2 * 4);
  float* Dinv = (float*)alloc((size_t)NN * 4);
  int* noff = (int*)alloc((size_t)(NN + 1) * 4);
  int* eoff = (int*)alloc((size_t)(MM + 1) * 4);
  int* em_n = (int*)alloc((size_t)EE * 4);
  int2* npos_e = (int2*)alloc((size_t)EE * 8);
  int* rank_n = (int*)alloc((size_t)EE * 4);
  int* rank_e = (int*)alloc((size_t)EE * 4);
  int* totN = (int*)alloc((size_t)NN * 4);
  int* totE = (int*)alloc((size_t)MM * 4);
  // zero region: cntN (8*NN), cntE (8*MM), bnst(4x256)
  size_t zero_bytes = ((size_t)NSLICE * (NN + MM) + 4 * 256) * 4;
  int* zero_region = (int*)alloc(zero_bytes);
  int* cntN = zero_region;
  int* cntE = cntN + NSLICE * NN;
  float* bnst = (float*)(cntE + NSLICE * MM);
  (void)ws_size;
  (void)in_sizes;
  (void)n_in;
  (void)out_size;

  (void)hipMemsetAsync(zero_region, 0, zero_bytes, stream);

  // CSR count (+ UVT for both layers in tail blocks)
  k_count_uv<<<NBC + 3, 256, 0, stream>>>(node_idx, edge_idx, cntN, cntE, rank_n,
                                          rank_e, linw1, att1, UVT1, linw2, att2,
                                          UVT2);
  k_slicescan<<<(NN + MM + 255) / 256, 256, 0, stream>>>(cntN, totN, cntE, totE);
  k_scan2<<<2, 1024, 0, stream>>>(totN, noff, totE, eoff);
  k_fill<<<NBC * NSLICE, 256, 0, stream>>>(node_idx, edge_idx, noff, eoff, cntN, cntE,
                                           rank_n, rank_e, em_n, npos_e);

  const float ninv = 1.f / (float)NN;
  const int gemm_grid = (NN + 63) / 64;
  const int cs_grid = (NN + 255) / 256;
  const int oute_grid = (MM + 31) / 32;
  const int dots_grid = (NN + 255) / 256;
  float* st0 = bnst + 0 * 256;
  float* st1 = bnst + 1 * 256;
  float* st2 = bnst + 2 * 256;
  float* st3 = bnst + 3 * 256;

  // buf0 = leaky(x@W1+b1) (raw pre-BN1), fused stats -> st0
  k_gemm128<<<gemm_grid, 256, 0, stream>>>(x, W1, b1, nullptr, nullptr, nullptr,
                                           nullptr, 0.f, buf0, st0, NN);

  // ---- hconv1 (H=4): h1 = BN1(buf0) applied inline ----
  k_dots<4><<<dots_grid, 256, 0, stream>>>((const float4*)buf0, NN, UVT1, st0, g1,
                                           be1, ninv, dotx, hv);
  k_dota<4><<<MM / 4, 256, 0, stream>>>(hv, eoff, npos_e, dota);
  k_softmax<4><<<NN / 4, 256, 0, stream>>>(noff, em_n, dotx, dota, wedge, alpha, Dinv);
  k_T<4><<<MM, 256, 0, stream>>>((const float4*)buf0, eoff, npos_e, alpha, st0, g1,
                                 be1, ninv, (float4*)Tbuf);
  {
    dim3 g(oute_grid, 4);
    k_oute32<4><<<g, 256, 0, stream>>>(Tbuf, linw1, eoff, wedge, oute);
  }
  k_phase9<4><<<NN / 4, 256, 0, stream>>>(noff, em_n, alpha, (const float4*)oute, Dinv,
                                          bias1, (const float4*)buf0, st0, g1, be1,
                                          ninv, (float4*)buf1);
  k_colstats<<<cs_grid, 256, 0, stream>>>((const float4*)buf1, NN, st1);

  // ---- hconv2 (H=1): h2 = BN2(buf1) applied inline ----
  k_dots<1><<<dots_grid, 256, 0, stream>>>((const float4*)buf1, NN, UVT2, st1, g2,
                                           be2, ninv, dotx, hv);
  k_dota<1><<<MM / 4, 256, 0, stream>>>(hv, eoff, npos_e, dota);
  k_softmax<1><<<NN / 4, 256, 0, stream>>>(noff, em_n, dotx, dota, wedge, alpha, Dinv);
  k_T<1><<<MM, 256, 0, stream>>>((const float4*)buf1, eoff, npos_e, alpha, st1, g2,
                                 be2, ninv, (float4*)Tbuf);
  {
    dim3 g(oute_grid, 1);
    k_oute32<1><<<g, 256, 0, stream>>>(Tbuf, linw2, eoff, wedge, oute);
  }
  k_phase9<1><<<NN / 4, 256, 0, stream>>>(noff, em_n, alpha, (const float4*)oute, Dinv,
                                          bias2, (const float4*)buf1, st1, g2, be2,
                                          ninv, (float4*)buf0);
  k_colstats<<<cs_grid, 256, 0, stream>>>((const float4*)buf0, NN, st2);

  // buf1 = leaky(BN3(buf0)@W2+b2) + x  (raw pre-BN4), fused stats -> st3
  k_gemm128<<<gemm_grid, 256, 0, stream>>>(buf0, W2, b2, x, st2, g3, be3, ninv, buf1,
                                           st3, NN);
  k_bnapply_final<<<(NN * 32 + 255) / 256, 256, 0, stream>>>(
      (const float4*)buf1, st3, g4, be4, ninv, (float4*)out, NN * 32);
}

// Round 9
// 313.472 us; speedup vs baseline: 1.1112x; 1.0716x over previous
//
#include <hip/hip_runtime.h>

// Problem constants (match reference)
#define NN 20000
#define MM 2000
#define EE 320000
#define NSLICE 8
#define NBC 1250  // EE/256 exactly
static constexpr float SLOPE = 0.2f;
static constexpr float EPSBN = 1e-5f;

__device__ inline float4 f4add(float4 a, float4 b) {
  return make_float4(a.x + b.x, a.y + b.y, a.z + b.z, a.w + b.w);
}
__device__ inline float4 f4fma(float a, float4 v, float4 c) {
  return make_float4(c.x + a * v.x, c.y + a * v.y, c.z + a * v.z, c.w + a * v.w);
}
__device__ inline float leaky(float v) { return (v > 0.f) ? v : SLOPE * v; }

// per-thread BN scale/shift for 4 channels (f4 index c4)
__device__ inline void bn_sc4(const float* __restrict__ st, const float* __restrict__ g,
                              const float* __restrict__ be, float ninv, int c4,
                              float4& sc, float4& sh) {
  float* scp = &sc.x;
  float* shp = &sh.x;
#pragma unroll
  for (int j = 0; j < 4; j++) {
    int c = c4 * 4 + j;
    float mu = st[c] * ninv;
    float var = st[128 + c] * ninv - mu * mu;
    float s = g[c] * rsqrtf(var + EPSBN);
    scp[j] = s;
    shp[j] = be[c] - mu * s;
  }
}

// ---------------------------------------------------------------------------
// CSR count (XCD-sliced counters) + both layers' UVT folded into tail blocks.
// ---------------------------------------------------------------------------
__global__ void k_count_uv(const int* __restrict__ ni, const int* __restrict__ ei,
                           int* cntN, int* cntE, int* __restrict__ rank_n,
                           int* __restrict__ rank_e, const float* __restrict__ linw1,
                           const float* __restrict__ att1, float* __restrict__ UVT1,
                           const float* __restrict__ linw2,
                           const float* __restrict__ att2, float* __restrict__ UVT2) {
  int b = blockIdx.x;
  if (b < NBC) {
    int e = b * 256 + threadIdx.x;
    int s = b & (NSLICE - 1);
    rank_n[e] = atomicAdd(&cntN[s * NN + ni[e]], 1);
    rank_e[e] = atomicAdd(&cntE[s * MM + ei[e]], 1);
  } else if (b < NBC + 2) {
    constexpr int H = 4;
    int idx = (b - NBC) * 256 + threadIdx.x;
    int h = idx >> 7, k = idx & 127;
    float u = 0.f, v = 0.f;
    for (int c = 0; c < 128; c++) {
      float w = linw1[(size_t)k * (128 * H) + h * 128 + c];
      u += w * att1[h * 256 + c];
      v += w * att1[h * 256 + 128 + c];
    }
    UVT1[h * 128 + k] = u;
    UVT1[(H + h) * 128 + k] = v;
  } else {
    if (threadIdx.x >= 128) return;
    int k = threadIdx.x;
    float u = 0.f, v = 0.f;
    for (int c = 0; c < 128; c++) {
      float w = linw2[(size_t)k * 128 + c];
      u += w * att2[c];
      v += w * att2[128 + c];
    }
    UVT2[k] = u;
    UVT2[128 + k] = v;
  }
}

// per-key exclusive scan over the 8 slices (parallel across keys);
// cnt[s][key] becomes within-key slice base, tot[key] = total.
__global__ void k_slicescan(int* __restrict__ cntN, int* __restrict__ totN,
                            int* __restrict__ cntE, int* __restrict__ totE) {
  int i = blockIdx.x * 256 + threadIdx.x;
  if (i < NN) {
    int run = 0;
#pragma unroll
    for (int s = 0; s < NSLICE; s++) {
      int t = cntN[s * NN + i];
      cntN[s * NN + i] = run;
      run += t;
    }
    totN[i] = run;
  } else if (i < NN + MM) {
    int m = i - NN;
    int run = 0;
#pragma unroll
    for (int s = 0; s < NSLICE; s++) {
      int t = cntE[s * MM + m];
      cntE[s * MM + m] = run;
      run += t;
    }
    totE[m] = run;
  }
}

// dual single-block exclusive scan (block 0: nodes, block 1: edges)
__global__ __launch_bounds__(1024) void k_scan2(const int* __restrict__ totN,
                                                int* __restrict__ noff,
                                                const int* __restrict__ totE,
                                                int* __restrict__ eoff) {
  const int* cnt = blockIdx.x ? totE : totN;
  int* off = blockIdx.x ? eoff : noff;
  int n = blockIdx.x ? MM : NN;
  __shared__ int swav[16];
  __shared__ int sCarry;
  int t = threadIdx.x;
  int lane = t & 63, wid = t >> 6;
  if (t == 0) sCarry = 0;
  __syncthreads();
  for (int base = 0; base < n; base += 1024) {
    int i = base + t;
    int v = (i < n) ? cnt[i] : 0;
    int x = v;
#pragma unroll
    for (int o = 1; o < 64; o <<= 1) {
      int y = __shfl_up(x, o);
      if (lane >= o) x += y;
    }
    if (lane == 63) swav[wid] = x;
    __syncthreads();
    if (wid == 0) {
      int s = (lane < 16) ? swav[lane] : 0;
#pragma unroll
      for (int o = 1; o < 16; o <<= 1) {
        int y = __shfl_up(s, o);
        if (lane >= o) s += y;
      }
      if (lane < 16) swav[lane] = s;
    }
    __syncthreads();
    int wpre = wid ? swav[wid - 1] : 0;
    int total = swav[15];
    if (i < n) off[i] = sCarry + wpre + x - v;
    __syncthreads();
    if (t == 0) sCarry += total;
    __syncthreads();
  }
  if (t == 0) off[n] = sCarry;
}

// atomic-free fill: position = off[key] + sliceBase[slice][key] + rank
__global__ void k_fill(const int* __restrict__ ni, const int* __restrict__ ei,
                       const int* __restrict__ noff, const int* __restrict__ eoff,
                       const int* __restrict__ cntN, const int* __restrict__ cntE,
                       const int* __restrict__ rank_n, const int* __restrict__ rank_e,
                       int* __restrict__ em_n, int2* __restrict__ npos_e) {
  int e = blockIdx.x * 256 + threadIdx.x;
  if (e >= EE) return;
  int s = blockIdx.x & (NSLICE - 1);
  int n = ni[e];
  int m = ei[e];
  int pn = noff[n] + cntN[s * NN + n] + rank_n[e];
  int pe = eoff[m] + cntE[s * MM + m] + rank_e[e];
  em_n[pn] = m;
  npos_e[pe] = make_int2(n, pn);
}

// ---------------------------------------------------------------------------
// Tiled GEMM: out = maybe_resid + leaky(BNopt(A)[rows,128] @ W[128,128] + b)
// Fused column stats (sum,sumsq) of the OUTPUT -> atomicAdd into stout.
// ---------------------------------------------------------------------------
__global__ __launch_bounds__(256) void k_gemm128(
    const float* __restrict__ A, const float* __restrict__ W,
    const float* __restrict__ bias, const float* __restrict__ resid,
    const float* __restrict__ st, const float* __restrict__ g,
    const float* __restrict__ be, float ninv, float* __restrict__ out,
    float* __restrict__ stout, int rows) {
  __shared__ float As[32][68];
  __shared__ float Ws[32][132];
  __shared__ float scs[128], shs[128];
  if (st && threadIdx.x < 128) {
    int c = threadIdx.x;
    float mu = st[c] * ninv;
    float var = st[128 + c] * ninv - mu * mu;
    float s = g[c] * rsqrtf(var + EPSBN);
    scs[c] = s;
    shs[c] = be[c] - mu * s;
  }
  if (st) __syncthreads();
  int tx = threadIdx.x & 15, ty = threadIdx.x >> 4;
  int r0 = blockIdx.x * 64;
  float4 acc[4][2];
#pragma unroll
  for (int j = 0; j < 4; j++) acc[j][0] = acc[j][1] = make_float4(0.f, 0.f, 0.f, 0.f);

  for (int k0 = 0; k0 < 128; k0 += 32) {
    __syncthreads();
    {
      int row = threadIdx.x >> 2, kq = threadIdx.x & 3;
      int rr = r0 + row;
      float4 a0 = make_float4(0.f, 0.f, 0.f, 0.f), a1 = a0;
      if (rr < rows) {
        const float* ap = A + (size_t)rr * 128 + k0 + kq * 8;
        a0 = ((const float4*)ap)[0];
        a1 = ((const float4*)ap)[1];
      }
      int kb = k0 + kq * 8;
      if (st) {
        a0.x = a0.x * scs[kb + 0] + shs[kb + 0];
        a0.y = a0.y * scs[kb + 1] + shs[kb + 1];
        a0.z = a0.z * scs[kb + 2] + shs[kb + 2];
        a0.w = a0.w * scs[kb + 3] + shs[kb + 3];
        a1.x = a1.x * scs[kb + 4] + shs[kb + 4];
        a1.y = a1.y * scs[kb + 5] + shs[kb + 5];
        a1.z = a1.z * scs[kb + 6] + shs[kb + 6];
        a1.w = a1.w * scs[kb + 7] + shs[kb + 7];
      }
      int kl = kq * 8;
      As[kl + 0][row] = a0.x;
      As[kl + 1][row] = a0.y;
      As[kl + 2][row] = a0.z;
      As[kl + 3][row] = a0.w;
      As[kl + 4][row] = a1.x;
      As[kl + 5][row] = a1.y;
      As[kl + 6][row] = a1.z;
      As[kl + 7][row] = a1.w;
    }
    {
      int kk = threadIdx.x >> 3, cq = threadIdx.x & 7;
      const float* wp = W + (size_t)(k0 + kk) * 128 + cq * 16;
#pragma unroll
      for (int f = 0; f < 4; f++)
        *(float4*)&Ws[kk][cq * 16 + f * 4] = ((const float4*)wp)[f];
    }
    __syncthreads();
#pragma unroll
    for (int kk = 0; kk < 32; kk++) {
      float4 a = *(const float4*)&As[kk][ty * 4];
      float4 w0 = *(const float4*)&Ws[kk][tx * 8];
      float4 w1 = *(const float4*)&Ws[kk][tx * 8 + 4];
      acc[0][0] = f4fma(a.x, w0, acc[0][0]);
      acc[0][1] = f4fma(a.x, w1, acc[0][1]);
      acc[1][0] = f4fma(a.y, w0, acc[1][0]);
      acc[1][1] = f4fma(a.y, w1, acc[1][1]);
      acc[2][0] = f4fma(a.z, w0, acc[2][0]);
      acc[2][1] = f4fma(a.z, w1, acc[2][1]);
      acc[3][0] = f4fma(a.w, w0, acc[3][0]);
      acc[3][1] = f4fma(a.w, w1, acc[3][1]);
    }
  }
  float4 b0 = ((const float4*)bias)[tx * 2];
  float4 b1 = ((const float4*)bias)[tx * 2 + 1];
  float4 cs0 = make_float4(0.f, 0.f, 0.f, 0.f), cs1 = cs0, cq0 = cs0, cq1 = cs0;
#pragma unroll
  for (int j = 0; j < 4; j++) {
    int r = r0 + ty * 4 + j;
    if (r < rows) {
      float4 o0 = acc[j][0], o1 = acc[j][1];
      o0 = make_float4(leaky(o0.x + b0.x), leaky(o0.y + b0.y), leaky(o0.z + b0.z),
                       leaky(o0.w + b0.w));
      o1 = make_float4(leaky(o1.x + b1.x), leaky(o1.y + b1.y), leaky(o1.z + b1.z),
                       leaky(o1.w + b1.w));
      if (resid) {
        float4 r0v = ((const float4*)resid)[(size_t)r * 32 + tx * 2];
        float4 r1v = ((const float4*)resid)[(size_t)r * 32 + tx * 2 + 1];
        o0 = f4add(o0, r0v);
        o1 = f4add(o1, r1v);
      }
      ((float4*)out)[(size_t)r * 32 + tx * 2] = o0;
      ((float4*)out)[(size_t)r * 32 + tx * 2 + 1] = o1;
      cs0 = f4add(cs0, o0);
      cs1 = f4add(cs1, o1);
      cq0 = make_float4(cq0.x + o0.x * o0.x, cq0.y + o0.y * o0.y, cq0.z + o0.z * o0.z,
                        cq0.w + o0.w * o0.w);
      cq1 = make_float4(cq1.x + o1.x * o1.x, cq1.y + o1.y * o1.y, cq1.z + o1.z * o1.z,
                        cq1.w + o1.w * o1.w);
    }
  }
  // fused column stats: reuse As (sum) / Ws (sumsq) LDS as [16][128]
  __syncthreads();
  float* sumb = &As[0][0];
  float* sqb = &Ws[0][0];
  *(float4*)&sumb[ty * 128 + tx * 8] = cs0;
  *(float4*)&sumb[ty * 128 + tx * 8 + 4] = cs1;
  *(float4*)&sqb[ty * 128 + tx * 8] = cq0;
  *(float4*)&sqb[ty * 128 + tx * 8 + 4] = cq1;
  __syncthreads();
  if (threadIdx.x < 128) {
    float S = 0.f, Q = 0.f;
#pragma unroll
    for (int w = 0; w < 16; w++) {
      S += sumb[w * 128 + threadIdx.x];
      Q += sqb[w * 128 + threadIdx.x];
    }
    atomicAdd(&stout[threadIdx.x], S);
    atomicAdd(&stout[128 + threadIdx.x], Q);
  }
}

// ---------------------------------------------------------------------------
// out_e[m][h][c] = (wedge[m]/deg) * (T[h][m][:] @ lin_w[:, h*128 + c])
// 64-row tiles (round-6 best config).
// ---------------------------------------------------------------------------
template <int H>
__global__ __launch_bounds__(256) void k_oute64(const float* __restrict__ T,
                                                const float* __restrict__ linw,
                                                const int* __restrict__ eoff,
                                                const float* __restrict__ wedge,
                                                float* __restrict__ oute) {
  int h = blockIdx.y;
  __shared__ float As[32][68];
  __shared__ float Ws[32][132];
  int tx = threadIdx.x & 15, ty = threadIdx.x >> 4;
  int r0 = blockIdx.x * 64;
  const float* A = T + (size_t)h * MM * 128;
  float4 acc[4][2];
#pragma unroll
  for (int j = 0; j < 4; j++) acc[j][0] = acc[j][1] = make_float4(0.f, 0.f, 0.f, 0.f);

  for (int k0 = 0; k0 < 128; k0 += 32) {
    __syncthreads();
    {
      int row = threadIdx.x >> 2, kq = threadIdx.x & 3;
      int rr = r0 + row;
      float4 a0 = make_float4(0.f, 0.f, 0.f, 0.f), a1 = a0;
      if (rr < MM) {
        const float* ap = A + (size_t)rr * 128 + k0 + kq * 8;
        a0 = ((const float4*)ap)[0];
        a1 = ((const float4*)ap)[1];
      }
      int kb = kq * 8;
      As[kb + 0][row] = a0.x;
      As[kb + 1][row] = a0.y;
      As[kb + 2][row] = a0.z;
      As[kb + 3][row] = a0.w;
      As[kb + 4][row] = a1.x;
      As[kb + 5][row] = a1.y;
      As[kb + 6][row] = a1.z;
      As[kb + 7][row] = a1.w;
    }
    {
      int kk = threadIdx.x >> 3, cq = threadIdx.x & 7;
      const float* wp = linw + (size_t)(k0 + kk) * (128 * H) + h * 128 + cq * 16;
#pragma unroll
      for (int f = 0; f < 4; f++)
        *(float4*)&Ws[kk][cq * 16 + f * 4] = ((const float4*)wp)[f];
    }
    __syncthreads();
#pragma unroll
    for (int kk = 0; kk < 32; kk++) {
      float4 a = *(const float4*)&As[kk][ty * 4];
      float4 w0 = *(const float4*)&Ws[kk][tx * 8];
      float4 w1 = *(const float4*)&Ws[kk][tx * 8 + 4];
      acc[0][0] = f4fma(a.x, w0, acc[0][0]);
      acc[0][1] = f4fma(a.x, w1, acc[0][1]);
      acc[1][0] = f4fma(a.y, w0, acc[1][0]);
      acc[1][1] = f4fma(a.y, w1, acc[1][1]);
      acc[2][0] = f4fma(a.z, w0, acc[2][0]);
      acc[2][1] = f4fma(a.z, w1, acc[2][1]);
      acc[3][0] = f4fma(a.w, w0, acc[3][0]);
      acc[3][1] = f4fma(a.w, w1, acc[3][1]);
    }
  }
#pragma unroll
  for (int j = 0; j < 4; j++) {
    int m = r0 + ty * 4 + j;
    if (m >= MM) break;
    int d = eoff[m + 1] - eoff[m];
    float bv = (d > 0) ? wedge[m] / (float)d : 0.f;
    float4 o0 = acc[j][0], o1 = acc[j][1];
    o0 = make_float4(bv * o0.x, bv * o0.y, bv * o0.z, bv * o0.w);
    o1 = make_float4(bv * o1.x, bv * o1.y, bv * o1.z, bv * o1.w);
    ((float4*)oute)[((size_t)m * H + h) * 32 + tx * 2] = o0;
    ((float4*)oute)[((size_t)m * H + h) * 32 + tx * 2 + 1] = o1;
  }
}

// ---------------------------------------------------------------------------
// BatchNorm column stats (sum, sumsq) -- standalone (for phase9 outputs)
// ---------------------------------------------------------------------------
__global__ __launch_bounds__(256) void k_colstats(const float4* __restrict__ X4,
                                                  int rows, float* __restrict__ st) {
  int c4 = threadIdx.x & 31, rs = threadIdx.x >> 5, wid = threadIdx.x >> 6;
  int r0 = blockIdx.x * 256;
  int rend = min(r0 + 256, rows);
  float4 s = make_float4(0.f, 0.f, 0.f, 0.f), q = s;
  for (int r = r0 + rs; r < rend; r += 8) {
    float4 v = X4[(size_t)r * 32 + c4];
    s = f4add(s, v);
    q = make_float4(q.x + v.x * v.x, q.y + v.y * v.y, q.z + v.z * v.z, q.w + v.w * v.w);
  }
  s.x += __shfl_xor(s.x, 32); s.y += __shfl_xor(s.y, 32);
  s.z += __shfl_xor(s.z, 32); s.w += __shfl_xor(s.w, 32);
  q.x += __shfl_xor(q.x, 32); q.y += __shfl_xor(q.y, 32);
  q.z += __shfl_xor(q.z, 32); q.w += __shfl_xor(q.w, 32);
  __shared__ float4 red[4][32][2];
  if ((threadIdx.x & 63) < 32) {
    red[wid][c4][0] = s;
    red[wid][c4][1] = q;
  }
  __syncthreads();
  if (threadIdx.x < 32) {
    float4 S = f4add(f4add(red[0][threadIdx.x][0], red[1][threadIdx.x][0]),
                     f4add(red[2][threadIdx.x][0], red[3][threadIdx.x][0]));
    float4 Q = f4add(f4add(red[0][threadIdx.x][1], red[1][threadIdx.x][1]),
                     f4add(red[2][threadIdx.x][1], red[3][threadIdx.x][1]));
    int c = threadIdx.x * 4;
    atomicAdd(&st[c + 0], S.x);
    atomicAdd(&st[c + 1], S.y);
    atomicAdd(&st[c + 2], S.z);
    atomicAdd(&st[c + 3], S.w);
    atomicAdd(&st[128 + c + 0], Q.x);
    atomicAdd(&st[128 + c + 1], Q.y);
    atomicAdd(&st[128 + c + 2], Q.z);
    atomicAdd(&st[128 + c + 3], Q.w);
  }
}

// final: out = BN(X) computed from raw stats
__global__ void k_bnapply_final(const float4* __restrict__ X4,
                                const float* __restrict__ st,
                                const float* __restrict__ g,
                                const float* __restrict__ be, float ninv,
                                float4* __restrict__ Y4, int total4) {
  int i = blockIdx.x * 256 + threadIdx.x;
  if (i >= total4) return;
  int c4 = i & 31;
  float4 sc, sh;
  bn_sc4(st, g, be, ninv, c4, sc, sh);
  float4 v = X4[i];
  Y4[i] = make_float4(v.x * sc.x + sh.x, v.y * sc.y + sh.y, v.z * sc.z + sh.z,
                      v.w * sc.w + sh.w);
}

// dotx[n,h] = BN(X)[n,:] . U[:,h] ; hv[n,h] = BN(X)[n,:] . V[:,h]
// (round-6 config: thread per (n,h2); 2H threads share a row)
template <int H>
__global__ void k_dots(const float4* __restrict__ X4, int rows,
                       const float* __restrict__ UVT, const float* __restrict__ st,
                       const float* __restrict__ g, const float* __restrict__ be,
                       float ninv, float* __restrict__ dotx, float* __restrict__ hv) {
  __shared__ float4 Ut[2 * H * 32];
  __shared__ float4 scl[32], shl[32];
  if (threadIdx.x < 32) {
    float4 sc, sh;
    bn_sc4(st, g, be, ninv, threadIdx.x, sc, sh);
    scl[threadIdx.x] = sc;
    shl[threadIdx.x] = sh;
  }
  for (int i = threadIdx.x; i < 2 * H * 32; i += 256) Ut[i] = ((const float4*)UVT)[i];
  __syncthreads();
  int idx = blockIdx.x * 256 + threadIdx.x;
  if (idx >= rows * 2 * H) return;
  int n = idx / (2 * H), h2 = idx - n * (2 * H);
  const float4* xr = X4 + (size_t)n * 32;
  const float4* ur = Ut + h2 * 32;
  float s = 0.f;
#pragma unroll 8
  for (int q = 0; q < 32; q++) {
    float4 a = xr[q], b = ur[q], c = scl[q], d = shl[q];
    float ax = a.x * c.x + d.x, ay = a.y * c.y + d.y;
    float az = a.z * c.z + d.z, aw = a.w * c.w + d.w;
    s += ax * b.x + ay * b.y + az * b.z + aw * b.w;
  }
  if (h2 < H)
    dotx[n * H + h2] = s;
  else
    hv[n * H + (h2 - H)] = s;
}

// dota[m,h] = sum over incidences of edge m of hv[node, h]
template <int H>
__global__ void k_dota(const float* __restrict__ hv, const int* __restrict__ eoff,
                       const int2* __restrict__ npos_e, float* __restrict__ dota) {
  int lane = threadIdx.x & 63;
  int m = blockIdx.x * 4 + (threadIdx.x >> 6);
  int s = eoff[m], t = eoff[m + 1];
  if (H == 4) {
    float4 acc = make_float4(0.f, 0.f, 0.f, 0.f);
    const float4* hv4 = (const float4*)hv;
    for (int j = s + lane; j < t; j += 64) acc = f4add(acc, hv4[npos_e[j].x]);
#pragma unroll
    for (int o = 32; o >= 1; o >>= 1) {
      acc.x += __shfl_xor(acc.x, o);
      acc.y += __shfl_xor(acc.y, o);
      acc.z += __shfl_xor(acc.z, o);
      acc.w += __shfl_xor(acc.w, o);
    }
    if (lane == 0) ((float4*)dota)[m] = acc;
  } else {
    float acc = 0.f;
    for (int j = s + lane; j < t; j += 64) acc += hv[npos_e[j].x];
#pragma unroll
    for (int o = 32; o >= 1; o >>= 1) acc += __shfl_xor(acc, o);
    if (lane == 0) dota[m] = acc;
  }
}

// ---------------------------------------------------------------------------
// Per-node segment softmax; alpha stored in node-CSR order.
// ---------------------------------------------------------------------------
template <int H>
__global__ void k_softmax(const int* __restrict__ noff, const int* __restrict__ em_n,
                          const float* __restrict__ dotx, const float* __restrict__ dota,
                          const float* __restrict__ wedge, float* __restrict__ alpha,
                          float* __restrict__ Dinv) {
  int lane = threadIdx.x & 63;
  int n = blockIdx.x * 4 + (threadIdx.x >> 6);
  int s = noff[n], t = noff[n + 1];
  int deg = t - s;
  int h = lane & (H - 1);
  float dx = dotx[n * H + h];
  if (deg <= 64) {
    int em0 = 0;
    float dd = 0.f;
    if (lane < deg) {
      em0 = em_n[s + lane];
      dd = wedge[em0];
    }
#pragma unroll
    for (int o = 32; o >= 1; o >>= 1) dd += __shfl_xor(dd, o);
    if (lane == 0) Dinv[n] = (dd > 0.f) ? 1.f / dd : 0.f;

    constexpr int KMAX = (H == 4) ? 4 : 1;
    int P = deg * H;
    float vc[KMAX];
    float mx = -3.0e38f;
#pragma unroll
    for (int k = 0; k < KMAX; k++) {
      int p = lane + 64 * k;
      int idx = (H == 4) ? (p >> 2) : p;
      int em = __shfl(em0, idx);
      float v = dx + dota[em * H + h];
      v = leaky(v);
      vc[k] = v;
      if (p < P) mx = fmaxf(mx, v);
    }
#pragma unroll
    for (int o = H; o < 64; o <<= 1) mx = fmaxf(mx, __shfl_xor(mx, o));
    float sm = 0.f;
#pragma unroll
    for (int k = 0; k < KMAX; k++) {
      int p = lane + 64 * k;
      float e = __expf(vc[k] - mx);
      vc[k] = e;
      if (p < P) sm += e;
    }
#pragma unroll
    for (int o = H; o < 64; o <<= 1) sm += __shfl_xor(sm, o);
    float inv = 1.f / (sm + 1e-16f);
#pragma unroll
    for (int k = 0; k < KMAX; k++) {
      int p = lane + 64 * k;
      if (p < P) alpha[s * H + p] = vc[k] * inv;
    }
  } else {
    float dd = 0.f;
    for (int i = s + lane; i < t; i += 64) dd += wedge[em_n[i]];
#pragma unroll
    for (int o = 32; o >= 1; o >>= 1) dd += __shfl_xor(dd, o);
    if (lane == 0) Dinv[n] = (dd > 0.f) ? 1.f / dd : 0.f;
    int P = deg * H;
    float mx = -3.0e38f;
    for (int p = lane; p < P; p += 64) {
      int i = s + ((H == 4) ? (p >> 2) : p);
      float v = leaky(dx + dota[em_n[i] * H + h]);
      mx = fmaxf(mx, v);
    }
#pragma unroll
    for (int o = H; o < 64; o <<= 1) mx = fmaxf(mx, __shfl_xor(mx, o));
    float sm = 0.f;
    for (int p = lane; p < P; p += 64) {
      int i = s + ((H == 4) ? (p >> 2) : p);
      float v = leaky(dx + dota[em_n[i] * H + h]);
      sm += __expf(v - mx);
    }
#pragma unroll
    for (int o = H; o < 64; o <<= 1) sm += __shfl_xor(sm, o);
    float inv = 1.f / (sm + 1e-16f);
    for (int p = lane; p < P; p += 64) {
      int i = s + ((H == 4) ? (p >> 2) : p);
      float v = leaky(dx + dota[em_n[i] * H + h]);
      alpha[s * H + p] = __expf(v - mx) * inv;
    }
  }
}

// ---------------------------------------------------------------------------
// T[h][m][c] = sc_c * (sum alpha * raw[node,c]) + sh_c * (sum alpha)
// BN factored out of the gather loop; packed LDS stage of {rowofs, alpha}.
// 8 slots x 32 lanes, block per edge m.
// ---------------------------------------------------------------------------
template <int H>
__global__ __launch_bounds__(256) void k_T(const float4* __restrict__ h4raw,
                                           const int* __restrict__ eoff,
                                           const int2* __restrict__ npos_e,
                                           const float* __restrict__ alpha,
                                           const float* __restrict__ st,
                                           const float* __restrict__ g,
                                           const float* __restrict__ be, float ninv,
                                           float4* __restrict__ T4) {
  int m = blockIdx.x;
  int slot = threadIdx.x >> 5, c = threadIdx.x & 31;
  int wv = threadIdx.x >> 6;
  int s = eoff[m], t = eoff[m + 1];
  __shared__ int sofs[256];
  __shared__ float sal[256 * H];
  __shared__ float4 red[4][H][32];
  __shared__ float4 redA[4];
  __shared__ float sAsum[4];
  float4 acc[H];
#pragma unroll
  for (int hh = 0; hh < H; hh++) acc[hh] = make_float4(0.f, 0.f, 0.f, 0.f);
  float4 asum = make_float4(0.f, 0.f, 0.f, 0.f);

  for (int c0 = s; c0 < t; c0 += 256) {
    int cnt = min(256, t - c0);
    __syncthreads();
    if (threadIdx.x < cnt) {
      int2 np = npos_e[c0 + threadIdx.x];
      sofs[threadIdx.x] = np.x * 32;
      if (H == 4) {
        float4 a4 = ((const float4*)alpha)[np.y];
        ((float4*)sal)[threadIdx.x] = a4;
        asum = f4add(asum, a4);
      } else {
        float a = alpha[np.y];
        sal[threadIdx.x] = a;
        asum.x += a;
      }
    }
    __syncthreads();
#pragma unroll 4
    for (int j = slot; j < cnt; j += 8) {
      int ofs = sofs[j];
      float4 v = h4raw[(size_t)ofs + c];
      if (H == 4) {
        float4 a4 = ((const float4*)sal)[j];
        acc[0] = f4fma(a4.x, v, acc[0]);
        acc[1 % H] = f4fma(a4.y, v, acc[1 % H]);
        acc[2 % H] = f4fma(a4.z, v, acc[2 % H]);
        acc[3 % H] = f4fma(a4.w, v, acc[3 % H]);
      } else {
        acc[0] = f4fma(sal[j], v, acc[0]);
      }
    }
  }
#pragma unroll
  for (int hh = 0; hh < H; hh++) {
    float4 a = acc[hh];
    a.x += __shfl_xor(a.x, 32); a.y += __shfl_xor(a.y, 32);
    a.z += __shfl_xor(a.z, 32); a.w += __shfl_xor(a.w, 32);
    acc[hh] = a;
  }
#pragma unroll
  for (int o = 32; o >= 1; o >>= 1) {
    asum.x += __shfl_xor(asum.x, o); asum.y += __shfl_xor(asum.y, o);
    asum.z += __shfl_xor(asum.z, o); asum.w += __shfl_xor(asum.w, o);
  }
  if ((threadIdx.x & 63) < 32) {
#pragma unroll
    for (int hh = 0; hh < H; hh++) red[wv][hh][c] = acc[hh];
  }
  if ((threadIdx.x & 63) == 0) redA[wv] = asum;
  __syncthreads();
  if (threadIdx.x == 0) {
    float4 A = f4add(f4add(redA[0], redA[1]), f4add(redA[2], redA[3]));
    sAsum[0] = A.x; sAsum[1] = A.y; sAsum[2] = A.z; sAsum[3] = A.w;
  }
  __syncthreads();
  if (threadIdx.x < 32 * H) {
    int hh = threadIdx.x >> 5, cc = threadIdx.x & 31;
    float4 r = f4add(f4add(red[0][hh][cc], red[1][hh][cc]),
                     f4add(red[2][hh][cc], red[3][hh][cc]));
    float as = sAsum[hh];
    float4 sc, sh;
    bn_sc4(st, g, be, ninv, cc, sc, sh);
    r = make_float4(sc.x * r.x + sh.x * as, sc.y * r.y + sh.y * as,
                    sc.z * r.z + sh.z * as, sc.w * r.w + sh.w * as);
    T4[((size_t)hh * MM + m) * 32 + cc] = r;
  }
}

// ---------------------------------------------------------------------------
// out[n,c] = BN(hres)[n,c] + Dinv[n]/H * sum alpha*oute[m,h,c] + bias
// One WAVE per node, no LDS/barriers.
// ---------------------------------------------------------------------------
template <int H>
__global__ __launch_bounds__(256) void k_phase9(
    const int* __restrict__ noff, const int* __restrict__ em_n,
    const float* __restrict__ alpha, const float4* __restrict__ oute4,
    const float* __restrict__ Dinv, const float* __restrict__ bias,
    const float4* __restrict__ hres4, const float* __restrict__ st,
    const float* __restrict__ g, const float* __restrict__ be, float ninv,
    float4* __restrict__ out4) {
  int wv = threadIdx.x >> 6, lane = threadIdx.x & 63;
  int n = blockIdx.x * 4 + wv;
  int slot = lane >> 5, c = lane & 31;
  int s = noff[n], t = noff[n + 1];
  int deg = t - s;
  float4 acc = make_float4(0.f, 0.f, 0.f, 0.f);
  if (deg <= 64) {
    int m_l = 0;
    float4 a_l = make_float4(0.f, 0.f, 0.f, 0.f);
    if (lane < deg) {
      m_l = em_n[s + lane];
      if (H == 4)
        a_l = ((const float4*)alpha)[s + lane];
      else
        a_l.x = alpha[s + lane];
    }
    for (int i = slot; i < deg; i += 2) {
      int m = __shfl(m_l, i);
      if (H == 4) {
        float ax = __shfl(a_l.x, i), ay = __shfl(a_l.y, i);
        float az = __shfl(a_l.z, i), aw = __shfl(a_l.w, i);
        const float4* base = oute4 + (size_t)m * 128 + c;
        acc = f4fma(ax, base[0], acc);
        acc = f4fma(ay, base[32], acc);
        acc = f4fma(az, base[64], acc);
        acc = f4fma(aw, base[96], acc);
      } else {
        float a = __shfl(a_l.x, i);
        acc = f4fma(a, oute4[(size_t)m * 32 + c], acc);
      }
    }
  } else {
    for (int i = s + slot; i < t; i += 2) {
      int m = em_n[i];
      if (H == 4) {
        float4 a4 = ((const float4*)alpha)[i];
        const float4* base = oute4 + (size_t)m * 128 + c;
        acc = f4fma(a4.x, base[0], acc);
        acc = f4fma(a4.y, base[32], acc);
        acc = f4fma(a4.z, base[64], acc);
        acc = f4fma(a4.w, base[96], acc);
      } else {
        acc = f4fma(alpha[i], oute4[(size_t)m * 32 + c], acc);
      }
    }
  }
  acc.x += __shfl_xor(acc.x, 32); acc.y += __shfl_xor(acc.y, 32);
  acc.z += __shfl_xor(acc.z, 32); acc.w += __shfl_xor(acc.w, 32);
  if (slot == 0) {
    float scn = Dinv[n] * (1.f / H);
    float4 scB, shB;
    bn_sc4(st, g, be, ninv, c, scB, shB);
    float4 hr = hres4[(size_t)n * 32 + c];
    hr = make_float4(hr.x * scB.x + shB.x, hr.y * scB.y + shB.y, hr.z * scB.z + shB.z,
                     hr.w * scB.w + shB.w);
    float4 bi = ((const float4*)bias)[c];
    out4[(size_t)n * 32 + c] =
        make_float4(hr.x + scn * acc.x + bi.x, hr.y + scn * acc.y + bi.y,
                    hr.z + scn * acc.z + bi.z, hr.w + scn * acc.w + bi.w);
  }
}

// ---------------------------------------------------------------------------
// Host side
// ---------------------------------------------------------------------------
static inline size_t alignup(size_t x) { return (x + 255) & ~(size_t)255; }

extern "C" void kernel_launch(void* const* d_in, const int* in_sizes, int n_in,
                              void* d_out, int out_size, void* d_ws, size_t ws_size,
                              hipStream_t stream) {
  const float* x = (const float*)d_in[0];
  const int* node_idx = (const int*)d_in[1];
  const int* edge_idx = (const int*)d_in[2];
  const float* wedge = (const float*)d_in[3];
  const float* W1 = (const float*)d_in[4];
  const float* b1 = (const float*)d_in[5];
  const float* g1 = (const float*)d_in[6];
  const float* be1 = (const float*)d_in[7];
  const float* linw1 = (const float*)d_in[8];
  const float* att1 = (const float*)d_in[9];
  const float* bias1 = (const float*)d_in[10];
  const float* g2 = (const float*)d_in[11];
  const float* be2 = (const float*)d_in[12];
  const float* linw2 = (const float*)d_in[13];
  const float* att2 = (const float*)d_in[14];
  const float* bias2 = (const float*)d_in[15];
  const float* g3 = (const float*)d_in[16];
  const float* be3 = (const float*)d_in[17];
  const float* W2 = (const float*)d_in[18];
  const float* b2 = (const float*)d_in[19];
  const float* g4 = (const float*)d_in[20];
  const float* be4 = (const float*)d_in[21];
  float* out = (float*)d_out;

  char* ws = (char*)d_ws;
  size_t off = 0;
  auto alloc = [&](size_t bytes) -> void* {
    void* p = ws + off;
    off = alignup(off + bytes);
    return p;
  };
  float* buf0 = (float*)alloc((size_t)NN * 128 * 4);
  float* buf1 = (float*)alloc((size_t)NN * 128 * 4);
  float* Tbuf = (float*)alloc((size_t)4 * MM * 128 * 4);
  float* oute = (float*)alloc((size_t)MM * 4 * 128 * 4);
  float* alpha = (float*)alloc((size_t)EE * 4 * 4);
  float* dotx = (float*)alloc((size_t)NN * 4 * 4);
  float* hv = (float*)alloc((size_t)NN * 4 * 4);
  float* dota = (float*)alloc((size_t)MM * 4 * 4);
  float* UVT1 = (float*)alloc(128 * 8 * 4);
  float* UVT2 = (float*)alloc(128 * 2 * 4);
  float* Dinv = (float*)alloc((size_t)NN * 4);
  int* noff = (int*)alloc((size_t)(NN + 1) * 4);
  int* eoff = (int*)alloc((size_t)(MM + 1) * 4);
  int* em_n = (int*)alloc((size_t)EE * 4);
  int2* npos_e = (int2*)alloc((size_t)EE * 8);
  int* rank_n = (int*)alloc((size_t)EE * 4);
  int* rank_e = (int*)alloc((size_t)EE * 4);
  int* totN = (int*)alloc((size_t)NN * 4);
  int* totE = (int*)alloc((size_t)MM * 4);
  // zero region: cntN (8*NN), cntE (8*MM), bnst(4x256)
  size_t zero_bytes = ((size_t)NSLICE * (NN + MM) + 4 * 256) * 4;
  int* zero_region = (int*)alloc(zero_bytes);
  int* cntN = zero_region;
  int* cntE = cntN + NSLICE * NN;
  float* bnst = (float*)(cntE + NSLICE * MM);
  (void)ws_size;
  (void)in_sizes;
  (void)n_in;
  (void)out_size;

  (void)hipMemsetAsync(zero_region, 0, zero_bytes, stream);

  // CSR count (+ UVT for both layers in tail blocks)
  k_count_uv<<<NBC + 3, 256, 0, stream>>>(node_idx, edge_idx, cntN, cntE, rank_n,
                                          rank_e, linw1, att1, UVT1, linw2, att2,
                                          UVT2);
  k_slicescan<<<(NN + MM + 255) / 256, 256, 0, stream>>>(cntN, totN, cntE, totE);
  k_scan2<<<2, 1024, 0, stream>>>(totN, noff, totE, eoff);
  k_fill<<<NBC, 256, 0, stream>>>(node_idx, edge_idx, noff, eoff, cntN, cntE, rank_n,
                                  rank_e, em_n, npos_e);

  const float ninv = 1.f / (float)NN;
  const int gemm_grid = (NN + 63) / 64;
  const int cs_grid = (NN + 255) / 256;
  const int oute_grid = (MM + 63) / 64;
  float* st0 = bnst + 0 * 256;
  float* st1 = bnst + 1 * 256;
  float* st2 = bnst + 2 * 256;
  float* st3 = bnst + 3 * 256;

  // buf0 = leaky(x@W1+b1) (raw pre-BN1), fused stats -> st0
  k_gemm128<<<gemm_grid, 256, 0, stream>>>(x, W1, b1, nullptr, nullptr, nullptr,
                                           nullptr, 0.f, buf0, st0, NN);

  // ---- hconv1 (H=4): h1 = BN1(buf0) applied inline ----
  k_dots<4><<<(NN * 8 + 255) / 256, 256, 0, stream>>>((const float4*)buf0, NN, UVT1,
                                                      st0, g1, be1, ninv, dotx, hv);
  k_dota<4><<<MM / 4, 256, 0, stream>>>(hv, eoff, npos_e, dota);
  k_softmax<4><<<NN / 4, 256, 0, stream>>>(noff, em_n, dotx, dota, wedge, alpha, Dinv);
  k_T<4><<<MM, 256, 0, stream>>>((const float4*)buf0, eoff, npos_e, alpha, st0, g1,
                                 be1, ninv, (float4*)Tbuf);
  {
    dim3 g(oute_grid, 4);
    k_oute64<4><<<g, 256, 0, stream>>>(Tbuf, linw1, eoff, wedge, oute);
  }
  k_phase9<4><<<NN / 4, 256, 0, stream>>>(noff, em_n, alpha, (const float4*)oute, Dinv,
                                          bias1, (const float4*)buf0, st0, g1, be1,
                                          ninv, (float4*)buf1);
  k_colstats<<<cs_grid, 256, 0, stream>>>((const float4*)buf1, NN, st1);

  // ---- hconv2 (H=1): h2 = BN2(buf1) applied inline ----
  k_dots<1><<<(NN * 2 + 255) / 256, 256, 0, stream>>>((const float4*)buf1, NN, UVT2,
                                                      st1, g2, be2, ninv, dotx, hv);
  k_dota<1><<<MM / 4, 256, 0, stream>>>(hv, eoff, npos_e, dota);
  k_softmax<1><<<NN / 4, 256, 0, stream>>>(noff, em_n, dotx, dota, wedge, alpha, Dinv);
  k_T<1><<<MM, 256, 0, stream>>>((const float4*)buf1, eoff, npos_e, alpha, st1, g2,
                                 be2, ninv, (float4*)Tbuf);
  {
    dim3 g(oute_grid, 1);
    k_oute64<1><<<g, 256, 0, stream>>>(Tbuf, linw2, eoff, wedge, oute);
  }
  k_phase9<1><<<NN / 4, 256, 0, stream>>>(noff, em_n, alpha, (const float4*)oute, Dinv,
                                          bias2, (const float4*)buf1, st1, g2, be2,
                                          ninv, (float4*)buf0);
  k_colstats<<<cs_grid, 256, 0, stream>>>((const float4*)buf0, NN, st2);

  // buf1 = leaky(BN3(buf0)@W2+b2) + x  (raw pre-BN4), fused stats -> st3
  k_gemm128<<<gemm_grid, 256, 0, stream>>>(buf0, W2, b2, x, st2, g3, be3, ninv, buf1,
                                           st3, NN);
  k_bnapply_final<<<(NN * 32 + 255) / 256, 256, 0, stream>>>(
      (const float4*)buf1, st3, g4, be4, ninv, (float4*)out, NN * 32);
}